// Round 9
// baseline (585.078 us; speedup 1.0000x reference)
//
#include <hip/hip_runtime.h>
#include <hip/hip_bf16.h>
#include <math.h>

// Problem dims
#define BB  4
#define TT  1024
#define DD  1024
#define HH  16
#define DH  64
#define DFF 4096
#define MHH 256

typedef __attribute__((ext_vector_type(8))) short bf16x8;   // 8 bf16 = 4 VGPRs
typedef __attribute__((ext_vector_type(4))) float f32x4;
typedef unsigned int u32;

#define NEG_BIG (-1e9f)

__device__ __forceinline__ float b2f(short s) {
    union { unsigned int u; float f; } x;
    x.u = ((unsigned int)(unsigned short)s) << 16;
    return x.f;
}
__device__ __forceinline__ short f2b(float f) {
    union { float f; unsigned int u; } x; x.f = f;
    unsigned int r = x.u + 0x7fffu + ((x.u >> 16) & 1u);   // RNE
    return (short)(r >> 16);
}
__device__ __forceinline__ float silu_f(float x) { return x / (1.f + __expf(-x)); }

// async global->LDS, 16B per lane. LDS dest must be wave_base + lane*16.
__device__ __forceinline__ void gld16(const short* g, short* l) {
    __builtin_amdgcn_global_load_lds(
        (const __attribute__((address_space(1))) u32*)g,
        (__attribute__((address_space(3))) u32*)l, 16, 0, 0);
}

// BK=64 staging: two BK=32 planes per buffer (proven layout per plane).
#define STAGE64(ga0, ga1, lds, kb)                                  \
    {                                                               \
        gld16((ga0) + (kb),      &(lds)[tid * 8]);                  \
        gld16((ga1) + (kb),      &(lds)[2048 + tid * 8]);           \
        gld16((ga0) + (kb) + 32, &(lds)[4096 + tid * 8]);           \
        gld16((ga1) + (kb) + 32, &(lds)[4096 + 2048 + tid * 8]);    \
    }

// ------------------- weight transpose tile: fp32 [K,N] -> bf16 [N,K] --------
__device__ __forceinline__ void convT_tile_body(
    const float* __restrict__ src, short* __restrict__ dst,
    int K, int N, int bx, int by, int tid, short (*Ts)[36])
{
    const int k0 = by * 32, n0 = bx * 32;
    const int r = tid >> 3, c4 = (tid & 7) * 4;
    float4 v = *(const float4*)(src + (size_t)(k0 + r) * N + n0 + c4);
    Ts[r][c4 + 0] = f2b(v.x); Ts[r][c4 + 1] = f2b(v.y);
    Ts[r][c4 + 2] = f2b(v.z); Ts[r][c4 + 3] = f2b(v.w);
    __syncthreads();
    short4 o;
    o.x = Ts[c4 + 0][r]; o.y = Ts[c4 + 1][r];
    o.z = Ts[c4 + 2][r]; o.w = Ts[c4 + 3][r];
    *(short4*)(dst + (size_t)(n0 + r) * K + k0 + c4) = o;
}

// ------------------------------- RMSNorm row body ---------------------------
// Optional XC: copy the fp32 input row to XC (folds the out=x memcpy into
// rmsnorm1's existing read of x). [verified r5]
__device__ __forceinline__ void rms_body(
    const float* __restrict__ X, const float* __restrict__ W,
    short* __restrict__ O, float* __restrict__ XC, int row, int tid, float* red)
{
    float4 xv = ((const float4*)(X + (size_t)row * DD))[tid];
    if (XC) ((float4*)(XC + (size_t)row * DD))[tid] = xv;
    float f0 = xv.x, f1 = xv.y, f2 = xv.z, f3 = xv.w;
    float ss = f0*f0 + f1*f1 + f2*f2 + f3*f3;
    #pragma unroll
    for (int m = 1; m < 64; m <<= 1) ss += __shfl_xor(ss, m);
    if ((tid & 63) == 0) red[tid >> 6] = ss;
    __syncthreads();
    float tot = red[0] + red[1] + red[2] + red[3];
    float scale = rsqrtf(tot * (1.f / DD) + 1e-6f);
    float4 wv = ((const float4*)W)[tid];
    short4 ov;
    ov.x = f2b(f0 * scale * wv.x);
    ov.y = f2b(f1 * scale * wv.y);
    ov.z = f2b(f2 * scale * wv.z);
    ov.w = f2b(f3 * scale * wv.w);
    ((short4*)(O + (size_t)row * DD))[tid] = ov;
}

// ---- fused pre-phase: weight transposes (4608 blocks) + rmsnorm1 (4096) ----
// Segments: wq(1024) wk(1024) wv(1024) mw1(256) wo(1024) mw2(256) | rms1(4096)
__global__ __launch_bounds__(256) void pre_k(
    const float* __restrict__ wq, const float* __restrict__ wk,
    const float* __restrict__ wv, const float* __restrict__ mw1,
    const float* __restrict__ wo, const float* __restrict__ mw2,
    short* __restrict__ WfT, short* __restrict__ woT, short* __restrict__ mw2T,
    const float* __restrict__ x, const float* __restrict__ n1w,
    short* __restrict__ h, float* __restrict__ out)
{
    __shared__ __align__(16) short Ts[32][36];
    __shared__ float red[4];
    const int b = blockIdx.x, tid = threadIdx.x;
    if (b >= 4608) { rms_body(x, n1w, h, out, b - 4608, tid, red); return; }
    const float* src; short* dst; int K, N, bx, by;
    if (b < 1024)      { src = wq;  dst = WfT;               K = DD;  N = DD;  int l = b;        bx = l & 31; by = l >> 5; }
    else if (b < 2048) { src = wk;  dst = WfT + 1024 * 1024; K = DD;  N = DD;  int l = b - 1024; bx = l & 31; by = l >> 5; }
    else if (b < 3072) { src = wv;  dst = WfT + 2048 * 1024; K = DD;  N = DD;  int l = b - 2048; bx = l & 31; by = l >> 5; }
    else if (b < 3328) { src = mw1; dst = WfT + 3072 * 1024; K = DD;  N = MHH; int l = b - 3072; bx = l & 7;  by = l >> 3; }
    else if (b < 4352) { src = wo;  dst = woT;               K = DD;  N = DD;  int l = b - 3328; bx = l & 31; by = l >> 5; }
    else               { src = mw2; dst = mw2T;              K = MHH; N = DD;  int l = b - 4352; bx = l & 31; by = l >> 5; }
    convT_tile_body(src, dst, K, N, bx, by, tid, Ts);
}

// ---- fused ffn-phase: gw/uw/dw transposes (12288 blocks) + rmsnorm2 (4096) -
__global__ __launch_bounds__(256) void ffn_k(
    const float* __restrict__ gw, const float* __restrict__ uw,
    const float* __restrict__ dw,
    short* __restrict__ WgT, short* __restrict__ WuT, short* __restrict__ WdT,
    const float* __restrict__ out, const float* __restrict__ n2w,
    short* __restrict__ h2)
{
    __shared__ __align__(16) short Ts[32][36];
    __shared__ float red[4];
    const int b = blockIdx.x, tid = threadIdx.x;
    if (b >= 12288) { rms_body(out, n2w, h2, nullptr, b - 12288, tid, red); return; }
    const float* src; short* dst; int K, N, bx, by;
    if (b < 4096)      { src = gw; dst = WgT; K = DD;  N = DFF; int l = b;        bx = l & 127; by = l >> 7; }
    else if (b < 8192) { src = uw; dst = WuT; K = DD;  N = DFF; int l = b - 4096; bx = l & 127; by = l >> 7; }
    else               { src = dw; dst = WdT; K = DFF; N = DD;  int l = b - 8192; bx = l & 31;  by = l >> 5; }
    convT_tile_body(src, dst, K, N, bx, by, tid, Ts);
}

// ------------- split-K 128x128 GEMM BK=64, fp32 atomic accumulate into out --
// __launch_bounds__(256, 4): single-acc body fits <=128 regs -> 4 waves/SIMD.
__global__ __launch_bounds__(256, 4) void gemm128_atomic_k(
    const short* __restrict__ A, const short* __restrict__ Bt,
    float* out, int N, int Kc, int lda, int ldb)
{
    __shared__ __align__(16) short As[2 * 4096];
    __shared__ __align__(16) short Bs[2 * 4096];
    const int tid  = threadIdx.x;
    const int wave = tid >> 6, lane = tid & 63;
    const int l16  = lane & 15, quad = lane >> 4;
    const int m0 = blockIdx.y * 128, n0 = blockIdx.x * 128;
    const int wm = (wave & 1) * 64, wn = (wave >> 1) * 64;
    const int koff = blockIdx.z * Kc;

    f32x4 acc[4][4];
    #pragma unroll
    for (int i = 0; i < 4; i++)
        #pragma unroll
        for (int j = 0; j < 4; j++) acc[i][j] = (f32x4){0.f, 0.f, 0.f, 0.f};

    const int srow = tid >> 2, scol = (tid & 3) * 8;
    const short* ga0 = A  + (size_t)(m0 + srow)      * lda + koff + scol;
    const short* ga1 = A  + (size_t)(m0 + 64 + srow) * lda + koff + scol;
    const short* gb0 = Bt + (size_t)(n0 + srow)      * ldb + koff + scol;
    const short* gb1 = Bt + (size_t)(n0 + 64 + srow) * ldb + koff + scol;

    for (int kb = 0; kb < Kc; kb += 64) {
        STAGE64(ga0, ga1, As, kb);
        STAGE64(gb0, gb1, Bs, kb);
        __syncthreads();
        #pragma unroll
        for (int kc = 0; kc < 2; kc++) {
            bf16x8 af[4], bf[4];
            #pragma unroll
            for (int mi = 0; mi < 4; mi++)
                af[mi] = *(bf16x8*)&As[kc * 4096 + (wm + mi * 16 + l16) * 32 + quad * 8];
            #pragma unroll
            for (int ni = 0; ni < 4; ni++)
                bf[ni] = *(bf16x8*)&Bs[kc * 4096 + (wn + ni * 16 + l16) * 32 + quad * 8];
            #pragma unroll
            for (int mi = 0; mi < 4; mi++)
                #pragma unroll
                for (int ni = 0; ni < 4; ni++)
                    acc[mi][ni] = __builtin_amdgcn_mfma_f32_16x16x32_bf16(af[mi], bf[ni], acc[mi][ni], 0, 0, 0);
        }
        __syncthreads();
    }
    #pragma unroll
    for (int mi = 0; mi < 4; mi++)
        #pragma unroll
        for (int ni = 0; ni < 4; ni++)
            #pragma unroll
            for (int r = 0; r < 4; r++) {
                int row = m0 + wm + mi * 16 + quad * 4 + r;
                int col = n0 + wn + ni * 16 + l16;
                atomicAdd(out + (size_t)row * N + col, acc[mi][ni][r]);
            }
}

// --------------- fused QKV+mnet1 GEMM: N=3328 packed weights, BK=64 ---------
// Wf rows: [0,1024)=wq^T, [1024,2048)=wk^T, [2048,3072)=wv^T, [3072,3328)=mw1^T
__global__ __launch_bounds__(256, 4) void gemm128_qkvm_k(
    const short* __restrict__ A, const short* __restrict__ Wf,
    short* __restrict__ Qb, short* __restrict__ Kb, short* __restrict__ Vb,
    short* __restrict__ M1)
{
    __shared__ __align__(16) short As[2 * 4096];
    __shared__ __align__(16) short Bs[2 * 4096];
    const int tid  = threadIdx.x;
    const int wave = tid >> 6, lane = tid & 63;
    const int l16  = lane & 15, quad = lane >> 4;
    const int m0 = blockIdx.y * 128, n0 = blockIdx.x * 128;
    const int wm = (wave & 1) * 64, wn = (wave >> 1) * 64;
    const int K = DD;

    f32x4 acc[4][4];
    #pragma unroll
    for (int i = 0; i < 4; i++)
        #pragma unroll
        for (int j = 0; j < 4; j++) acc[i][j] = (f32x4){0.f, 0.f, 0.f, 0.f};

    const int srow = tid >> 2, scol = (tid & 3) * 8;
    const short* ga0 = A  + (size_t)(m0 + srow)      * K + scol;
    const short* ga1 = A  + (size_t)(m0 + 64 + srow) * K + scol;
    const short* gb0 = Wf + (size_t)(n0 + srow)      * K + scol;
    const short* gb1 = Wf + (size_t)(n0 + 64 + srow) * K + scol;

    for (int kb = 0; kb < K; kb += 64) {
        STAGE64(ga0, ga1, As, kb);
        STAGE64(gb0, gb1, Bs, kb);
        __syncthreads();
        #pragma unroll
        for (int kc = 0; kc < 2; kc++) {
            bf16x8 af[4], bf[4];
            #pragma unroll
            for (int mi = 0; mi < 4; mi++)
                af[mi] = *(bf16x8*)&As[kc * 4096 + (wm + mi * 16 + l16) * 32 + quad * 8];
            #pragma unroll
            for (int ni = 0; ni < 4; ni++)
                bf[ni] = *(bf16x8*)&Bs[kc * 4096 + (wn + ni * 16 + l16) * 32 + quad * 8];
            #pragma unroll
            for (int mi = 0; mi < 4; mi++)
                #pragma unroll
                for (int ni = 0; ni < 4; ni++)
                    acc[mi][ni] = __builtin_amdgcn_mfma_f32_16x16x32_bf16(af[mi], bf[ni], acc[mi][ni], 0, 0, 0);
        }
        __syncthreads();
    }
    short* dst; int base, ldc; bool dosilu = false;
    if      (n0 < 1024) { dst = Qb; base = 0;    ldc = 1024; }
    else if (n0 < 2048) { dst = Kb; base = 1024; ldc = 1024; }
    else if (n0 < 3072) { dst = Vb; base = 2048; ldc = 1024; }
    else                { dst = M1; base = 3072; ldc = 256; dosilu = true; }
    #pragma unroll
    for (int mi = 0; mi < 4; mi++)
        #pragma unroll
        for (int ni = 0; ni < 4; ni++)
            #pragma unroll
            for (int r = 0; r < 4; r++) {
                int row = m0 + wm + mi * 16 + quad * 4 + r;
                int col = n0 + wn + ni * 16 + l16 - base;
                float v = acc[mi][ni][r];
                if (dosilu) v = silu_f(v);
                dst[(size_t)row * ldc + col] = f2b(v);
            }
}

// ----- mnet2 GEMM (K=256) with fused softplus + gkc epilogue ----------------
// g = softplus(m1 @ mw2T); then in-register: gk = g*k into KG (in-place over
// the K projection), cj[b,h,t] = sum_d gk*k. Per (mi,r) each wave's l16-group
// covers exactly one 64-dim head (cols n0+wn .. +63), so the d-sum is a
// 16-lane shfl_xor tree -- no atomics, each (row,head) written once.
// Numerics match gkc_k: g rounded to bf16 BEFORE g*k; cc uses unrounded p*k.
__global__ __launch_bounds__(256, 4) void gemm128_mnet2_k(
    const short* __restrict__ A, const short* __restrict__ Bt,
    short* __restrict__ G, short* KG, float* __restrict__ Cj)
{
    __shared__ __align__(16) short As[2 * 4096];
    __shared__ __align__(16) short Bs[2 * 4096];
    const int tid  = threadIdx.x;
    const int wave = tid >> 6, lane = tid & 63;
    const int l16  = lane & 15, quad = lane >> 4;
    const int m0 = blockIdx.y * 128, n0 = blockIdx.x * 128;
    const int wm = (wave & 1) * 64, wn = (wave >> 1) * 64;
    const int K = MHH;

    f32x4 acc[4][4];
    #pragma unroll
    for (int i = 0; i < 4; i++)
        #pragma unroll
        for (int j = 0; j < 4; j++) acc[i][j] = (f32x4){0.f, 0.f, 0.f, 0.f};

    const int srow = tid >> 2, scol = (tid & 3) * 8;
    const short* ga0 = A  + (size_t)(m0 + srow)      * K + scol;
    const short* ga1 = A  + (size_t)(m0 + 64 + srow) * K + scol;
    const short* gb0 = Bt + (size_t)(n0 + srow)      * K + scol;
    const short* gb1 = Bt + (size_t)(n0 + 64 + srow) * K + scol;

    for (int kk = 0; kk < K; kk += 64) {
        STAGE64(ga0, ga1, As, kk);
        STAGE64(gb0, gb1, Bs, kk);
        __syncthreads();
        #pragma unroll
        for (int kc = 0; kc < 2; kc++) {
            bf16x8 af[4], bf[4];
            #pragma unroll
            for (int mi = 0; mi < 4; mi++)
                af[mi] = *(bf16x8*)&As[kc * 4096 + (wm + mi * 16 + l16) * 32 + quad * 8];
            #pragma unroll
            for (int ni = 0; ni < 4; ni++)
                bf[ni] = *(bf16x8*)&Bs[kc * 4096 + (wn + ni * 16 + l16) * 32 + quad * 8];
            #pragma unroll
            for (int mi = 0; mi < 4; mi++)
                #pragma unroll
                for (int ni = 0; ni < 4; ni++)
                    acc[mi][ni] = __builtin_amdgcn_mfma_f32_16x16x32_bf16(af[mi], bf[ni], acc[mi][ni], 0, 0, 0);
        }
        __syncthreads();
    }
    const int hidx = (n0 + wn) >> 6;   // head covered by this wave's 64 cols
    #pragma unroll
    for (int mi = 0; mi < 4; mi++) {
        #pragma unroll
        for (int r = 0; r < 4; r++) {
            const int row = m0 + wm + mi * 16 + quad * 4 + r;
            float ccv = 0.f;
            #pragma unroll
            for (int ni = 0; ni < 4; ni++) {
                const int col = n0 + wn + ni * 16 + l16;
                const size_t idx = (size_t)row * DD + col;
                float v = acc[mi][ni][r];
                v = fmaxf(v, 0.f) + log1pf(__expf(-fabsf(v)));   // softplus
                short gb = f2b(v);
                G[idx] = gb;
                float gf = b2f(gb);
                float kf = b2f(KG[idx]);
                float p  = gf * kf;
                KG[idx] = f2b(p);
                ccv += p * kf;
            }
            #pragma unroll
            for (int m = 1; m < 16; m <<= 1) ccv += __shfl_xor(ccv, m);
            if (l16 == 0) {
                int bidx = row >> 10, t = row & (TT - 1);
                Cj[((size_t)bidx * HH + hidx) * TT + t] = ccv;
            }
        }
    }
}

// ------------------------- 128x128 fused SwiGLU (gate & up) GEMM, BK=64 -----
// __launch_bounds__(256, 2): dual acc (128 acc regs) overflows 256 total at
// default build -> 1 wave/SIMD. Forcing 2 waves/EU doubles occupancy.
// [verified r4/r5: 133 -> 76 us, MfmaUtil 37% = 2-phase structure ceiling]
__global__ __launch_bounds__(256, 2) void gemm128_swiglu_k(
    const short* __restrict__ A, const short* __restrict__ Gt,
    const short* __restrict__ Ut, short* __restrict__ F,
    int N, int K, int ldb)
{
    __shared__ __align__(16) short As[2 * 4096];
    __shared__ __align__(16) short Gs[2 * 4096];
    __shared__ __align__(16) short Us[2 * 4096];
    const int tid  = threadIdx.x;
    const int wave = tid >> 6, lane = tid & 63;
    const int l16  = lane & 15, quad = lane >> 4;

    int bx = blockIdx.x, by = blockIdx.y;
    {
        const int gx = gridDim.x;
        if ((gx & 7) == 0) {
            const int orig = by * gx + bx;          // x-fastest dispatch order
            const int xcd = orig & 7, j = orig >> 3;
            const int xpx = gx >> 3;                // n-tiles per XCD
            bx = xcd * xpx + (j % xpx);
            by = j / xpx;
        }
    }
    const int m0 = by * 128, n0 = bx * 128;
    const int wm = (wave & 1) * 64, wn = (wave >> 1) * 64;

    f32x4 ag[4][4], au[4][4];
    #pragma unroll
    for (int i = 0; i < 4; i++)
        #pragma unroll
        for (int j = 0; j < 4; j++) {
            ag[i][j] = (f32x4){0.f, 0.f, 0.f, 0.f};
            au[i][j] = (f32x4){0.f, 0.f, 0.f, 0.f};
        }

    const int srow = tid >> 2, scol = (tid & 3) * 8;
    const short* ga0 = A  + (size_t)(m0 + srow)      * K   + scol;
    const short* ga1 = A  + (size_t)(m0 + 64 + srow) * K   + scol;
    const short* gg0 = Gt + (size_t)(n0 + srow)      * ldb + scol;
    const short* gg1 = Gt + (size_t)(n0 + 64 + srow) * ldb + scol;
    const short* gu0 = Ut + (size_t)(n0 + srow)      * ldb + scol;
    const short* gu1 = Ut + (size_t)(n0 + 64 + srow) * ldb + scol;

    for (int kb = 0; kb < K; kb += 64) {
        STAGE64(ga0, ga1, As, kb);
        STAGE64(gg0, gg1, Gs, kb);
        STAGE64(gu0, gu1, Us, kb);
        __syncthreads();
        #pragma unroll
        for (int kc = 0; kc < 2; kc++) {
            bf16x8 af[4], gf[4], uf[4];
            #pragma unroll
            for (int mi = 0; mi < 4; mi++)
                af[mi] = *(bf16x8*)&As[kc * 4096 + (wm + mi * 16 + l16) * 32 + quad * 8];
            #pragma unroll
            for (int ni = 0; ni < 4; ni++) {
                gf[ni] = *(bf16x8*)&Gs[kc * 4096 + (wn + ni * 16 + l16) * 32 + quad * 8];
                uf[ni] = *(bf16x8*)&Us[kc * 4096 + (wn + ni * 16 + l16) * 32 + quad * 8];
            }
            #pragma unroll
            for (int mi = 0; mi < 4; mi++)
                #pragma unroll
                for (int ni = 0; ni < 4; ni++) {
                    ag[mi][ni] = __builtin_amdgcn_mfma_f32_16x16x32_bf16(af[mi], gf[ni], ag[mi][ni], 0, 0, 0);
                    au[mi][ni] = __builtin_amdgcn_mfma_f32_16x16x32_bf16(af[mi], uf[ni], au[mi][ni], 0, 0, 0);
                }
        }
        __syncthreads();
    }
    #pragma unroll
    for (int mi = 0; mi < 4; mi++)
        #pragma unroll
        for (int ni = 0; ni < 4; ni++)
            #pragma unroll
            for (int r = 0; r < 4; r++) {
                int row = m0 + wm + mi * 16 + quad * 4 + r;
                int col = n0 + wn + ni * 16 + l16;
                F[(size_t)row * N + col] = f2b(silu_f(ag[mi][ni][r]) * au[mi][ni][r]);
            }
}

// -------------------------------------------------- flash geodesic attention -
// Vt store XOR-swizzle (G4): unswizzled, lanes 0-7 write rows differing by 8
// at stride 72 shorts -> delta 288 words === 0 mod 32 -> 8-way bank conflict
// on all 16 transpose stores per KV-tile. Swizzle col ^= ((row>>3)&7)<<3
// (store side: (row>>3)&7 == tid&7) spreads the 8 lanes over 8 banks; the
// matching read-side XOR keeps 16B alignment and the read's free 2-way.
__global__ __launch_bounds__(256) void attn_k(
    const short* __restrict__ Q, const short* __restrict__ G,
    const short* __restrict__ GK, const short* __restrict__ V,
    const float* __restrict__ Cj, short* __restrict__ O)
{
    __shared__ __align__(16) short Gs[64][72];
    __shared__ __align__(16) short GKs[64][72];
    __shared__ __align__(16) short Vt[64][72];
    __shared__ __align__(16) float Cs[64];
    __shared__ __align__(16) short Ps[4][16][72];

    const int pair = blockIdx.x;          // 0..7
    const int bh = blockIdx.y;
    const int b = bh >> 4, h = bh & 15;
    const int tid  = threadIdx.x;
    const int wave = tid >> 6, lane = tid & 63;
    const int l16  = lane & 15, quad = lane >> 4;

    const size_t bh_base = ((size_t)b * TT) * (HH * DH) + (size_t)h * DH;
    const float* cj_row = Cj + ((size_t)b * HH + h) * TT;

    const int sr2 = tid >> 3, sc2 = (tid & 7) * 8;
    const int vswz = (tid & 7) << 3;      // = ((row>>3)&7)<<3 for store rows
    const f32x4 z = {0.f, 0.f, 0.f, 0.f};

    for (int halfsel = 0; halfsel < 2; halfsel++) {
        const int it = halfsel ? 15 - pair : pair;
        const int i0 = it * 64;

        const int qrow = i0 + wave * 16 + l16;
        bf16x8 qf[2], qqf[2];
        #pragma unroll
        for (int kc = 0; kc < 2; kc++) {
            qf[kc] = *(const bf16x8*)(Q + bh_base + (size_t)qrow * (HH * DH) + kc * 32 + quad * 8);
            #pragma unroll
            for (int j = 0; j < 8; j++) {
                float f = b2f(qf[kc][j]);
                qqf[kc][j] = f2b(f * f);
            }
        }

        float m_i[4], l_i[4];
        f32x4 o_acc[4] = {z, z, z, z};
        #pragma unroll
        for (int r = 0; r < 4; r++) { m_i[r] = NEG_BIG; l_i[r] = 0.f; }

        for (int jt = 0; jt <= it; jt++) {
            const int j0 = jt * 64;
            #pragma unroll
            for (int pass = 0; pass < 2; pass++) {
                int jr = sr2 + pass * 32;
                size_t rb = bh_base + (size_t)(j0 + jr) * (HH * DH) + sc2;
                *(int4*)&Gs[jr][sc2]  = *(const int4*)(G + rb);
                *(int4*)&GKs[jr][sc2] = *(const int4*)(GK + rb);
                int4 vvec = *(const int4*)(V + rb);
                const short* vv = (const short*)&vvec;
                #pragma unroll
                for (int jj = 0; jj < 8; jj++) Vt[sc2 + jj][jr ^ vswz] = vv[jj];
            }
            if (tid < 64) Cs[tid] = cj_row[j0 + tid];
            __syncthreads();

            f32x4 s1[4] = {z, z, z, z}, s2[4] = {z, z, z, z};
            #pragma unroll
            for (int ns = 0; ns < 4; ns++) {
                #pragma unroll
                for (int kc = 0; kc < 2; kc++) {
                    bf16x8 gf  = *(bf16x8*)&Gs [ns * 16 + l16][kc * 32 + quad * 8];
                    bf16x8 gkf = *(bf16x8*)&GKs[ns * 16 + l16][kc * 32 + quad * 8];
                    s1[ns] = __builtin_amdgcn_mfma_f32_16x16x32_bf16(qqf[kc], gf,  s1[ns], 0, 0, 0);
                    s2[ns] = __builtin_amdgcn_mfma_f32_16x16x32_bf16(qf[kc],  gkf, s2[ns], 0, 0, 0);
                }
            }

            float p[4][4];
            #pragma unroll
            for (int ns = 0; ns < 4; ns++) {
                float cjv = Cs[ns * 16 + l16];
                #pragma unroll
                for (int r = 0; r < 4; r++)
                    p[ns][r] = (2.f * s2[ns][r] - s1[ns][r] - cjv) * 0.125f;
            }
            if (jt == it) {
                #pragma unroll
                for (int ns = 0; ns < 4; ns++) {
                    int j = j0 + ns * 16 + l16;
                    #pragma unroll
                    for (int r = 0; r < 4; r++) {
                        int i = i0 + wave * 16 + quad * 4 + r;
                        if (j > i) p[ns][r] = NEG_BIG;
                    }
                }
            }

            #pragma unroll
            for (int r = 0; r < 4; r++) {
                float mx = fmaxf(fmaxf(p[0][r], p[1][r]), fmaxf(p[2][r], p[3][r]));
                #pragma unroll
                for (int d2 = 1; d2 < 16; d2 <<= 1) mx = fmaxf(mx, __shfl_xor(mx, d2));
                float mnew = fmaxf(m_i[r], mx);
                float corr = __expf(m_i[r] - mnew);
                float sp = 0.f;
                #pragma unroll
                for (int ns = 0; ns < 4; ns++) {
                    float e = __expf(p[ns][r] - mnew);
                    p[ns][r] = e; sp += e;
                }
                #pragma unroll
                for (int d2 = 1; d2 < 16; d2 <<= 1) sp += __shfl_xor(sp, d2);
                l_i[r] = l_i[r] * corr + sp;
                m_i[r] = mnew;
                #pragma unroll
                for (int nv = 0; nv < 4; nv++) o_acc[nv][r] *= corr;
            }

            #pragma unroll
            for (int ns = 0; ns < 4; ns++)
                #pragma unroll
                for (int r = 0; r < 4; r++)
                    Ps[wave][quad * 4 + r][ns * 16 + l16] = f2b(p[ns][r]);

            bf16x8 pf[2];
            pf[0] = *(bf16x8*)&Ps[wave][l16][quad * 8];
            pf[1] = *(bf16x8*)&Ps[wave][l16][32 + quad * 8];
            #pragma unroll
            for (int nv = 0; nv < 4; nv++) {
                const int vx = ((2 * nv + (l16 >> 3)) & 7) << 3;   // read-side XOR
                #pragma unroll
                for (int kc = 0; kc < 2; kc++) {
                    bf16x8 vf = *(bf16x8*)&Vt[nv * 16 + l16][(kc * 32 + quad * 8) ^ vx];
                    o_acc[nv] = __builtin_amdgcn_mfma_f32_16x16x32_bf16(pf[kc], vf, o_acc[nv], 0, 0, 0);
                }
            }
            __syncthreads();
        }

        #pragma unroll
        for (int nv = 0; nv < 4; nv++) {
            #pragma unroll
            for (int r = 0; r < 4; r++) {
                int i = i0 + wave * 16 + quad * 4 + r;
                int d = nv * 16 + l16;
                O[bh_base + (size_t)i * (HH * DH) + d] = f2b(o_acc[nv][r] / l_i[r]);
            }
        }
    }
}

// ------------------------------------------------------------------ launch ---
extern "C" void kernel_launch(void* const* d_in, const int* in_sizes, int n_in,
                              void* d_out, int out_size, void* d_ws, size_t ws_size,
                              hipStream_t stream)
{
    const float* x   = (const float*)d_in[0];
    const float* n1w = (const float*)d_in[1];
    const float* n2w = (const float*)d_in[2];
    const float* wq  = (const float*)d_in[3];
    const float* wk  = (const float*)d_in[4];
    const float* wv  = (const float*)d_in[5];
    const float* wo  = (const float*)d_in[6];
    const float* mw1 = (const float*)d_in[7];
    const float* mw2 = (const float*)d_in[8];
    const float* gw  = (const float*)d_in[9];
    const float* uw  = (const float*)d_in[10];
    const float* dw  = (const float*)d_in[11];
    float* out = (float*)d_out;   // fp32; holds x2 = x + attn@wo after wo-phase

    // Arena (48 MB known-safe; F widens to 32 MB iff ws_size >= 64 MB):
    //  slot0: h -> g -> h2 | slot1: qb -> WgT | slot2: kb/gk -> WuT
    //  slot3: vb -> WdT    | slot4(32-40): WfT(6.8M) -> ob; F overlays 32..
    //  slot5(40-48): woT(2M)@40 | m1(2M)@42 | cj(.25M)@44 | mw2T(.5M)@44.5 -> F
    const size_t MB = 1u << 20;
    if (ws_size < 48 * MB) return;
    const bool bigF = (ws_size >= 64 * MB);
    char* wsb = (char*)d_ws;
    short* h    = (short*)(wsb);
    short* g    = (short*)(wsb);
    short* h2   = (short*)(wsb);
    short* qb   = (short*)(wsb + 8 * MB);
    short* WgT  = (short*)(wsb + 8 * MB);
    short* kb   = (short*)(wsb + 16 * MB);
    short* WuT  = (short*)(wsb + 16 * MB);
    short* vb   = (short*)(wsb + 24 * MB);
    short* WdT  = (short*)(wsb + 24 * MB);
    short* WfT  = (short*)(wsb + 32 * MB);   // 3328x1024 bf16 = 6.8 MB
    short* ob   = (short*)(wsb + 32 * MB);
    short* F    = (short*)(wsb + 32 * MB);   // 16 MB (32 MB if bigF)
    short* woT  = (short*)(wsb + 40 * MB);
    short* m1   = (short*)(wsb + 42 * MB);
    float* cj   = (float*)(wsb + 44 * MB);
    short* mw2T = (short*)(wsb + 44 * MB + 512 * 1024);

    const int M = BB * TT;  // 4096 token rows

    // pre-attention weight transposes + rmsnorm1 (+ x->out copy), one dispatch
    pre_k<<<4608 + M, 256, 0, stream>>>(wq, wk, wv, mw1, wo, mw2,
                                        WfT, woT, mw2T, x, n1w, h, out);

    gemm128_qkvm_k<<<dim3(3328 / 128, M / 128), 256, 0, stream>>>(h, WfT, qb, kb, vb, m1);

    // mnet2 GEMM with fused softplus + gk/cj epilogue (replaces mnet2 + gkc)
    gemm128_mnet2_k<<<dim3(DD / 128, M / 128), 256, 0, stream>>>(m1, mw2T, g, kb, cj);

    attn_k<<<dim3(8, BB * HH), 256, 0, stream>>>(qb, g, kb, vb, cj, ob);

    // out (= x) += ob @ wo  (split-K=2, fp32 atomic accumulate)
    gemm128_atomic_k<<<dim3(DD / 128, M / 128, 2), 256, 0, stream>>>(
        ob, woT, out, DD, 512, DD, DD);

    // FFN weight transposes + rmsnorm2, one dispatch (WgT/WuT/WdT overlay
    // qb/kb/vb -> must be after attn; rms2 needs out after wo-atomic)
    ffn_k<<<12288 + M, 256, 0, stream>>>(gw, uw, dw, WgT, WuT, WdT, out, n2w, h2);

    if (bigF) {   // one full-width SwiGLU (1024 blocks) + split-K=2 down
        gemm128_swiglu_k<<<dim3(DFF / 128, M / 128), 256, 0, stream>>>(h2, WgT, WuT, F, DFF, DD, DD);
        gemm128_atomic_k<<<dim3(DD / 128, M / 128, 2), 256, 0, stream>>>(
            F, WdT, out, DD, 2048, DFF, DFF);
    } else {      // two 2048-col halves, each with split-K=2 down
        const int NH = DFF / 2;
        for (int half = 0; half < 2; half++) {
            gemm128_swiglu_k<<<dim3(NH / 128, M / 128), 256, 0, stream>>>(
                h2, WgT + (size_t)half * NH * DD, WuT + (size_t)half * NH * DD, F, NH, DD, DD);
            gemm128_atomic_k<<<dim3(DD / 128, M / 128, 2), 256, 0, stream>>>(
                F, WdT + (size_t)half * NH, out, DD, 1024, NH, DFF);
        }
    }
}

// Round 10
// 546.807 us; speedup vs baseline: 1.0700x; 1.0700x over previous
//
#include <hip/hip_runtime.h>
#include <hip/hip_bf16.h>
#include <math.h>

// Problem dims
#define BB  4
#define TT  1024
#define DD  1024
#define HH  16
#define DH  64
#define DFF 4096
#define MHH 256

typedef __attribute__((ext_vector_type(8))) short bf16x8;   // 8 bf16 = 4 VGPRs
typedef __attribute__((ext_vector_type(4))) float f32x4;
typedef unsigned int u32;

#define NEG_BIG (-1e9f)

__device__ __forceinline__ float b2f(short s) {
    union { unsigned int u; float f; } x;
    x.u = ((unsigned int)(unsigned short)s) << 16;
    return x.f;
}
__device__ __forceinline__ short f2b(float f) {
    union { float f; unsigned int u; } x; x.f = f;
    unsigned int r = x.u + 0x7fffu + ((x.u >> 16) & 1u);   // RNE
    return (short)(r >> 16);
}
__device__ __forceinline__ float silu_f(float x) { return x / (1.f + __expf(-x)); }

// async global->LDS, 16B per lane. LDS dest must be wave_base + lane*16.
__device__ __forceinline__ void gld16(const short* g, short* l) {
    __builtin_amdgcn_global_load_lds(
        (const __attribute__((address_space(1))) u32*)g,
        (__attribute__((address_space(3))) u32*)l, 16, 0, 0);
}

// BK=64 staging: two BK=32 planes per buffer (proven layout per plane).
#define STAGE64(ga0, ga1, lds, kb)                                  \
    {                                                               \
        gld16((ga0) + (kb),      &(lds)[tid * 8]);                  \
        gld16((ga1) + (kb),      &(lds)[2048 + tid * 8]);           \
        gld16((ga0) + (kb) + 32, &(lds)[4096 + tid * 8]);           \
        gld16((ga1) + (kb) + 32, &(lds)[4096 + 2048 + tid * 8]);    \
    }

// ------------------- weight transpose tile: fp32 [K,N] -> bf16 [N,K] --------
__device__ __forceinline__ void convT_tile_body(
    const float* __restrict__ src, short* __restrict__ dst,
    int K, int N, int bx, int by, int tid, short (*Ts)[36])
{
    const int k0 = by * 32, n0 = bx * 32;
    const int r = tid >> 3, c4 = (tid & 7) * 4;
    float4 v = *(const float4*)(src + (size_t)(k0 + r) * N + n0 + c4);
    Ts[r][c4 + 0] = f2b(v.x); Ts[r][c4 + 1] = f2b(v.y);
    Ts[r][c4 + 2] = f2b(v.z); Ts[r][c4 + 3] = f2b(v.w);
    __syncthreads();
    short4 o;
    o.x = Ts[c4 + 0][r]; o.y = Ts[c4 + 1][r];
    o.z = Ts[c4 + 2][r]; o.w = Ts[c4 + 3][r];
    *(short4*)(dst + (size_t)(n0 + r) * K + k0 + c4) = o;
}

// ------------------------------- RMSNorm row body ---------------------------
// Optional XC: copy the fp32 input row to XC (folds the out=x memcpy into
// rmsnorm1's existing read of x). [verified r5]
__device__ __forceinline__ void rms_body(
    const float* __restrict__ X, const float* __restrict__ W,
    short* __restrict__ O, float* __restrict__ XC, int row, int tid, float* red)
{
    float4 xv = ((const float4*)(X + (size_t)row * DD))[tid];
    if (XC) ((float4*)(XC + (size_t)row * DD))[tid] = xv;
    float f0 = xv.x, f1 = xv.y, f2 = xv.z, f3 = xv.w;
    float ss = f0*f0 + f1*f1 + f2*f2 + f3*f3;
    #pragma unroll
    for (int m = 1; m < 64; m <<= 1) ss += __shfl_xor(ss, m);
    if ((tid & 63) == 0) red[tid >> 6] = ss;
    __syncthreads();
    float tot = red[0] + red[1] + red[2] + red[3];
    float scale = rsqrtf(tot * (1.f / DD) + 1e-6f);
    float4 wv = ((const float4*)W)[tid];
    short4 ov;
    ov.x = f2b(f0 * scale * wv.x);
    ov.y = f2b(f1 * scale * wv.y);
    ov.z = f2b(f2 * scale * wv.z);
    ov.w = f2b(f3 * scale * wv.w);
    ((short4*)(O + (size_t)row * DD))[tid] = ov;
}

// ---- fused pre-phase: weight transposes (4608 blocks) + rmsnorm1 (4096) ----
// Segments: wq(1024) wk(1024) wv(1024) mw1(256) wo(1024) mw2(256) | rms1(4096)
__global__ __launch_bounds__(256) void pre_k(
    const float* __restrict__ wq, const float* __restrict__ wk,
    const float* __restrict__ wv, const float* __restrict__ mw1,
    const float* __restrict__ wo, const float* __restrict__ mw2,
    short* __restrict__ WfT, short* __restrict__ woT, short* __restrict__ mw2T,
    const float* __restrict__ x, const float* __restrict__ n1w,
    short* __restrict__ h, float* __restrict__ out)
{
    __shared__ __align__(16) short Ts[32][36];
    __shared__ float red[4];
    const int b = blockIdx.x, tid = threadIdx.x;
    if (b >= 4608) { rms_body(x, n1w, h, out, b - 4608, tid, red); return; }
    const float* src; short* dst; int K, N, bx, by;
    if (b < 1024)      { src = wq;  dst = WfT;               K = DD;  N = DD;  int l = b;        bx = l & 31; by = l >> 5; }
    else if (b < 2048) { src = wk;  dst = WfT + 1024 * 1024; K = DD;  N = DD;  int l = b - 1024; bx = l & 31; by = l >> 5; }
    else if (b < 3072) { src = wv;  dst = WfT + 2048 * 1024; K = DD;  N = DD;  int l = b - 2048; bx = l & 31; by = l >> 5; }
    else if (b < 3328) { src = mw1; dst = WfT + 3072 * 1024; K = DD;  N = MHH; int l = b - 3072; bx = l & 7;  by = l >> 3; }
    else if (b < 4352) { src = wo;  dst = woT;               K = DD;  N = DD;  int l = b - 3328; bx = l & 31; by = l >> 5; }
    else               { src = mw2; dst = mw2T;              K = MHH; N = DD;  int l = b - 4352; bx = l & 31; by = l >> 5; }
    convT_tile_body(src, dst, K, N, bx, by, tid, Ts);
}

// ---- fused ffn-phase: gw/uw/dw transposes (12288 blocks) + rmsnorm2 (4096) -
__global__ __launch_bounds__(256) void ffn_k(
    const float* __restrict__ gw, const float* __restrict__ uw,
    const float* __restrict__ dw,
    short* __restrict__ WgT, short* __restrict__ WuT, short* __restrict__ WdT,
    const float* __restrict__ out, const float* __restrict__ n2w,
    short* __restrict__ h2)
{
    __shared__ __align__(16) short Ts[32][36];
    __shared__ float red[4];
    const int b = blockIdx.x, tid = threadIdx.x;
    if (b >= 12288) { rms_body(out, n2w, h2, nullptr, b - 12288, tid, red); return; }
    const float* src; short* dst; int K, N, bx, by;
    if (b < 4096)      { src = gw; dst = WgT; K = DD;  N = DFF; int l = b;        bx = l & 127; by = l >> 7; }
    else if (b < 8192) { src = uw; dst = WuT; K = DD;  N = DFF; int l = b - 4096; bx = l & 127; by = l >> 7; }
    else               { src = dw; dst = WdT; K = DFF; N = DD;  int l = b - 8192; bx = l & 31;  by = l >> 5; }
    convT_tile_body(src, dst, K, N, bx, by, tid, Ts);
}

// --------------------------------------------- 128x128 MFMA GEMM, BK=64 -----
// __launch_bounds__(256, 4): single-acc body fits <=128 regs -> 4 waves/SIMD.
#define EP_NONE     0
#define EP_SILU     1
#define EP_SOFTPLUS 2
#define EP_RES      3

template<int EP, bool CF32, bool AUXF32>
__global__ __launch_bounds__(256, 4) void gemm128_k(
    const short* __restrict__ A, const short* __restrict__ Bt,
    void* Cv, const void* auxv,
    int N, int K, int lda, int ldb)
{
    __shared__ __align__(16) short As[2 * 4096];   // 2 planes of 128x32
    __shared__ __align__(16) short Bs[2 * 4096];
    const int tid  = threadIdx.x;
    const int wave = tid >> 6, lane = tid & 63;
    const int l16  = lane & 15, quad = lane >> 4;
    const int m0 = blockIdx.y * 128, n0 = blockIdx.x * 128;
    const int wm = (wave & 1) * 64, wn = (wave >> 1) * 64;

    f32x4 acc[4][4];
    #pragma unroll
    for (int i = 0; i < 4; i++)
        #pragma unroll
        for (int j = 0; j < 4; j++) acc[i][j] = (f32x4){0.f, 0.f, 0.f, 0.f};

    const int srow = tid >> 2, scol = (tid & 3) * 8;
    const short* ga0 = A  + (size_t)(m0 + srow)      * lda + scol;
    const short* ga1 = A  + (size_t)(m0 + 64 + srow) * lda + scol;
    const short* gb0 = Bt + (size_t)(n0 + srow)      * ldb + scol;
    const short* gb1 = Bt + (size_t)(n0 + 64 + srow) * ldb + scol;

    for (int kb = 0; kb < K; kb += 64) {
        STAGE64(ga0, ga1, As, kb);
        STAGE64(gb0, gb1, Bs, kb);
        __syncthreads();
        #pragma unroll
        for (int kc = 0; kc < 2; kc++) {
            bf16x8 af[4], bf[4];
            #pragma unroll
            for (int mi = 0; mi < 4; mi++)
                af[mi] = *(bf16x8*)&As[kc * 4096 + (wm + mi * 16 + l16) * 32 + quad * 8];
            #pragma unroll
            for (int ni = 0; ni < 4; ni++)
                bf[ni] = *(bf16x8*)&Bs[kc * 4096 + (wn + ni * 16 + l16) * 32 + quad * 8];
            #pragma unroll
            for (int mi = 0; mi < 4; mi++)
                #pragma unroll
                for (int ni = 0; ni < 4; ni++)
                    acc[mi][ni] = __builtin_amdgcn_mfma_f32_16x16x32_bf16(af[mi], bf[ni], acc[mi][ni], 0, 0, 0);
        }
        __syncthreads();
    }
    #pragma unroll
    for (int mi = 0; mi < 4; mi++) {
        #pragma unroll
        for (int ni = 0; ni < 4; ni++) {
            #pragma unroll
            for (int r = 0; r < 4; r++) {
                int row = m0 + wm + mi * 16 + quad * 4 + r;
                int col = n0 + wn + ni * 16 + l16;
                size_t idx = (size_t)row * N + col;
                float v = acc[mi][ni][r];
                if (EP == EP_SILU)          v = silu_f(v);
                else if (EP == EP_SOFTPLUS) v = fmaxf(v, 0.f) + log1pf(__expf(-fabsf(v)));
                else if (EP == EP_RES) {
                    if (AUXF32) v += ((const float*)auxv)[idx];
                    else        v += b2f(((const short*)auxv)[idx]);
                }
                if (CF32) ((float*)Cv)[idx] = v;
                else      ((short*)Cv)[idx] = f2b(v);
            }
        }
    }
}

// ------------- split-K 128x128 GEMM BK=64, fp32 atomic accumulate into out --
__global__ __launch_bounds__(256, 4) void gemm128_atomic_k(
    const short* __restrict__ A, const short* __restrict__ Bt,
    float* out, int N, int Kc, int lda, int ldb)
{
    __shared__ __align__(16) short As[2 * 4096];
    __shared__ __align__(16) short Bs[2 * 4096];
    const int tid  = threadIdx.x;
    const int wave = tid >> 6, lane = tid & 63;
    const int l16  = lane & 15, quad = lane >> 4;
    const int m0 = blockIdx.y * 128, n0 = blockIdx.x * 128;
    const int wm = (wave & 1) * 64, wn = (wave >> 1) * 64;
    const int koff = blockIdx.z * Kc;

    f32x4 acc[4][4];
    #pragma unroll
    for (int i = 0; i < 4; i++)
        #pragma unroll
        for (int j = 0; j < 4; j++) acc[i][j] = (f32x4){0.f, 0.f, 0.f, 0.f};

    const int srow = tid >> 2, scol = (tid & 3) * 8;
    const short* ga0 = A  + (size_t)(m0 + srow)      * lda + koff + scol;
    const short* ga1 = A  + (size_t)(m0 + 64 + srow) * lda + koff + scol;
    const short* gb0 = Bt + (size_t)(n0 + srow)      * ldb + koff + scol;
    const short* gb1 = Bt + (size_t)(n0 + 64 + srow) * ldb + koff + scol;

    for (int kb = 0; kb < Kc; kb += 64) {
        STAGE64(ga0, ga1, As, kb);
        STAGE64(gb0, gb1, Bs, kb);
        __syncthreads();
        #pragma unroll
        for (int kc = 0; kc < 2; kc++) {
            bf16x8 af[4], bf[4];
            #pragma unroll
            for (int mi = 0; mi < 4; mi++)
                af[mi] = *(bf16x8*)&As[kc * 4096 + (wm + mi * 16 + l16) * 32 + quad * 8];
            #pragma unroll
            for (int ni = 0; ni < 4; ni++)
                bf[ni] = *(bf16x8*)&Bs[kc * 4096 + (wn + ni * 16 + l16) * 32 + quad * 8];
            #pragma unroll
            for (int mi = 0; mi < 4; mi++)
                #pragma unroll
                for (int ni = 0; ni < 4; ni++)
                    acc[mi][ni] = __builtin_amdgcn_mfma_f32_16x16x32_bf16(af[mi], bf[ni], acc[mi][ni], 0, 0, 0);
        }
        __syncthreads();
    }
    #pragma unroll
    for (int mi = 0; mi < 4; mi++)
        #pragma unroll
        for (int ni = 0; ni < 4; ni++)
            #pragma unroll
            for (int r = 0; r < 4; r++) {
                int row = m0 + wm + mi * 16 + quad * 4 + r;
                int col = n0 + wn + ni * 16 + l16;
                atomicAdd(out + (size_t)row * N + col, acc[mi][ni][r]);
            }
}

// --------------- fused QKV+mnet1 GEMM: N=3328 packed weights, BK=64 ---------
// Wf rows: [0,1024)=wq^T, [1024,2048)=wk^T, [2048,3072)=wv^T, [3072,3328)=mw1^T
__global__ __launch_bounds__(256, 4) void gemm128_qkvm_k(
    const short* __restrict__ A, const short* __restrict__ Wf,
    short* __restrict__ Qb, short* __restrict__ Kb, short* __restrict__ Vb,
    short* __restrict__ M1)
{
    __shared__ __align__(16) short As[2 * 4096];
    __shared__ __align__(16) short Bs[2 * 4096];
    const int tid  = threadIdx.x;
    const int wave = tid >> 6, lane = tid & 63;
    const int l16  = lane & 15, quad = lane >> 4;
    const int m0 = blockIdx.y * 128, n0 = blockIdx.x * 128;
    const int wm = (wave & 1) * 64, wn = (wave >> 1) * 64;
    const int K = DD;

    f32x4 acc[4][4];
    #pragma unroll
    for (int i = 0; i < 4; i++)
        #pragma unroll
        for (int j = 0; j < 4; j++) acc[i][j] = (f32x4){0.f, 0.f, 0.f, 0.f};

    const int srow = tid >> 2, scol = (tid & 3) * 8;
    const short* ga0 = A  + (size_t)(m0 + srow)      * K + scol;
    const short* ga1 = A  + (size_t)(m0 + 64 + srow) * K + scol;
    const short* gb0 = Wf + (size_t)(n0 + srow)      * K + scol;
    const short* gb1 = Wf + (size_t)(n0 + 64 + srow) * K + scol;

    for (int kb = 0; kb < K; kb += 64) {
        STAGE64(ga0, ga1, As, kb);
        STAGE64(gb0, gb1, Bs, kb);
        __syncthreads();
        #pragma unroll
        for (int kc = 0; kc < 2; kc++) {
            bf16x8 af[4], bf[4];
            #pragma unroll
            for (int mi = 0; mi < 4; mi++)
                af[mi] = *(bf16x8*)&As[kc * 4096 + (wm + mi * 16 + l16) * 32 + quad * 8];
            #pragma unroll
            for (int ni = 0; ni < 4; ni++)
                bf[ni] = *(bf16x8*)&Bs[kc * 4096 + (wn + ni * 16 + l16) * 32 + quad * 8];
            #pragma unroll
            for (int mi = 0; mi < 4; mi++)
                #pragma unroll
                for (int ni = 0; ni < 4; ni++)
                    acc[mi][ni] = __builtin_amdgcn_mfma_f32_16x16x32_bf16(af[mi], bf[ni], acc[mi][ni], 0, 0, 0);
        }
        __syncthreads();
    }
    short* dst; int base, ldc; bool dosilu = false;
    if      (n0 < 1024) { dst = Qb; base = 0;    ldc = 1024; }
    else if (n0 < 2048) { dst = Kb; base = 1024; ldc = 1024; }
    else if (n0 < 3072) { dst = Vb; base = 2048; ldc = 1024; }
    else                { dst = M1; base = 3072; ldc = 256; dosilu = true; }
    #pragma unroll
    for (int mi = 0; mi < 4; mi++)
        #pragma unroll
        for (int ni = 0; ni < 4; ni++)
            #pragma unroll
            for (int r = 0; r < 4; r++) {
                int row = m0 + wm + mi * 16 + quad * 4 + r;
                int col = n0 + wn + ni * 16 + l16 - base;
                float v = acc[mi][ni][r];
                if (dosilu) v = silu_f(v);
                dst[(size_t)row * ldc + col] = f2b(v);
            }
}

// ------------------------- 128x128 fused SwiGLU (gate & up) GEMM, BK=64 -----
// __launch_bounds__(256, 2): dual acc (128 acc regs) overflows 256 total at
// default build -> 1 wave/SIMD. Forcing 2 waves/EU doubles occupancy.
// [verified r4/r5: 133 -> 76 us, MfmaUtil 37% = 2-phase structure ceiling]
__global__ __launch_bounds__(256, 2) void gemm128_swiglu_k(
    const short* __restrict__ A, const short* __restrict__ Gt,
    const short* __restrict__ Ut, short* __restrict__ F,
    int N, int K, int ldb)
{
    __shared__ __align__(16) short As[2 * 4096];
    __shared__ __align__(16) short Gs[2 * 4096];
    __shared__ __align__(16) short Us[2 * 4096];
    const int tid  = threadIdx.x;
    const int wave = tid >> 6, lane = tid & 63;
    const int l16  = lane & 15, quad = lane >> 4;

    int bx = blockIdx.x, by = blockIdx.y;
    {
        const int gx = gridDim.x;
        if ((gx & 7) == 0) {
            const int orig = by * gx + bx;          // x-fastest dispatch order
            const int xcd = orig & 7, j = orig >> 3;
            const int xpx = gx >> 3;                // n-tiles per XCD
            bx = xcd * xpx + (j % xpx);
            by = j / xpx;
        }
    }
    const int m0 = by * 128, n0 = bx * 128;
    const int wm = (wave & 1) * 64, wn = (wave >> 1) * 64;

    f32x4 ag[4][4], au[4][4];
    #pragma unroll
    for (int i = 0; i < 4; i++)
        #pragma unroll
        for (int j = 0; j < 4; j++) {
            ag[i][j] = (f32x4){0.f, 0.f, 0.f, 0.f};
            au[i][j] = (f32x4){0.f, 0.f, 0.f, 0.f};
        }

    const int srow = tid >> 2, scol = (tid & 3) * 8;
    const short* ga0 = A  + (size_t)(m0 + srow)      * K   + scol;
    const short* ga1 = A  + (size_t)(m0 + 64 + srow) * K   + scol;
    const short* gg0 = Gt + (size_t)(n0 + srow)      * ldb + scol;
    const short* gg1 = Gt + (size_t)(n0 + 64 + srow) * ldb + scol;
    const short* gu0 = Ut + (size_t)(n0 + srow)      * ldb + scol;
    const short* gu1 = Ut + (size_t)(n0 + 64 + srow) * ldb + scol;

    for (int kb = 0; kb < K; kb += 64) {
        STAGE64(ga0, ga1, As, kb);
        STAGE64(gg0, gg1, Gs, kb);
        STAGE64(gu0, gu1, Us, kb);
        __syncthreads();
        #pragma unroll
        for (int kc = 0; kc < 2; kc++) {
            bf16x8 af[4], gf[4], uf[4];
            #pragma unroll
            for (int mi = 0; mi < 4; mi++)
                af[mi] = *(bf16x8*)&As[kc * 4096 + (wm + mi * 16 + l16) * 32 + quad * 8];
            #pragma unroll
            for (int ni = 0; ni < 4; ni++) {
                gf[ni] = *(bf16x8*)&Gs[kc * 4096 + (wn + ni * 16 + l16) * 32 + quad * 8];
                uf[ni] = *(bf16x8*)&Us[kc * 4096 + (wn + ni * 16 + l16) * 32 + quad * 8];
            }
            #pragma unroll
            for (int mi = 0; mi < 4; mi++)
                #pragma unroll
                for (int ni = 0; ni < 4; ni++) {
                    ag[mi][ni] = __builtin_amdgcn_mfma_f32_16x16x32_bf16(af[mi], gf[ni], ag[mi][ni], 0, 0, 0);
                    au[mi][ni] = __builtin_amdgcn_mfma_f32_16x16x32_bf16(af[mi], uf[ni], au[mi][ni], 0, 0, 0);
                }
        }
        __syncthreads();
    }
    #pragma unroll
    for (int mi = 0; mi < 4; mi++)
        #pragma unroll
        for (int ni = 0; ni < 4; ni++)
            #pragma unroll
            for (int r = 0; r < 4; r++) {
                int row = m0 + wm + mi * 16 + quad * 4 + r;
                int col = n0 + wn + ni * 16 + l16;
                F[(size_t)row * N + col] = f2b(silu_f(ag[mi][ni][r]) * au[mi][ni][r]);
            }
}

// ------------------------------------- gk = g*k in-place, c = sum gk*k ------
__global__ __launch_bounds__(256) void gkc_k(
    const short* __restrict__ G, short* KG,
    float* __restrict__ Cj)
{
    const int bt  = blockIdx.x;
    const int tid = threadIdx.x;
    const int h = tid >> 4, d0 = (tid & 15) * 4;
    const size_t base = (size_t)bt * (HH * DH) + h * DH + d0;
    short4 gv = *(const short4*)(G + base);
    short4 kv = *(const short4*)(KG + base);
    float g0 = b2f(gv.x), g1 = b2f(gv.y), g2 = b2f(gv.z), g3 = b2f(gv.w);
    float k0 = b2f(kv.x), k1 = b2f(kv.y), k2 = b2f(kv.z), k3 = b2f(kv.w);
    float p0 = g0*k0, p1 = g1*k1, p2 = g2*k2, p3 = g3*k3;
    short4 ov; ov.x = f2b(p0); ov.y = f2b(p1); ov.z = f2b(p2); ov.w = f2b(p3);
    *(short4*)(KG + base) = ov;
    float cc = p0*k0 + p1*k1 + p2*k2 + p3*k3;
    #pragma unroll
    for (int m = 1; m < 16; m <<= 1) cc += __shfl_xor(cc, m);
    if ((tid & 15) == 0) {
        int b = bt >> 10, t = bt & (TT - 1);
        Cj[((size_t)b * HH + h) * TT + t] = cc;
    }
}

// -------------------------------------------------- flash geodesic attention -
// Vt store XOR-swizzle (G4): unswizzled, lanes 0-7 write rows differing by 8
// at stride 72 shorts -> delta 288 words === 0 mod 32 -> 8-way bank conflict
// on all 16 transpose stores per KV-tile. Swizzle col ^= ((row>>3)&7)<<3
// (store side: (row>>3)&7 == tid&7) spreads the 8 lanes over 8 banks; the
// matching read-side XOR keeps 16B alignment and the read's free 2-way.
// [r9: refcheck'd (absmax unchanged); perf isolated this round]
__global__ __launch_bounds__(256) void attn_k(
    const short* __restrict__ Q, const short* __restrict__ G,
    const short* __restrict__ GK, const short* __restrict__ V,
    const float* __restrict__ Cj, short* __restrict__ O)
{
    __shared__ __align__(16) short Gs[64][72];
    __shared__ __align__(16) short GKs[64][72];
    __shared__ __align__(16) short Vt[64][72];
    __shared__ __align__(16) float Cs[64];
    __shared__ __align__(16) short Ps[4][16][72];

    const int pair = blockIdx.x;          // 0..7
    const int bh = blockIdx.y;
    const int b = bh >> 4, h = bh & 15;
    const int tid  = threadIdx.x;
    const int wave = tid >> 6, lane = tid & 63;
    const int l16  = lane & 15, quad = lane >> 4;

    const size_t bh_base = ((size_t)b * TT) * (HH * DH) + (size_t)h * DH;
    const float* cj_row = Cj + ((size_t)b * HH + h) * TT;

    const int sr2 = tid >> 3, sc2 = (tid & 7) * 8;
    const int vswz = (tid & 7) << 3;      // = ((row>>3)&7)<<3 for store rows
    const f32x4 z = {0.f, 0.f, 0.f, 0.f};

    for (int halfsel = 0; halfsel < 2; halfsel++) {
        const int it = halfsel ? 15 - pair : pair;
        const int i0 = it * 64;

        const int qrow = i0 + wave * 16 + l16;
        bf16x8 qf[2], qqf[2];
        #pragma unroll
        for (int kc = 0; kc < 2; kc++) {
            qf[kc] = *(const bf16x8*)(Q + bh_base + (size_t)qrow * (HH * DH) + kc * 32 + quad * 8);
            #pragma unroll
            for (int j = 0; j < 8; j++) {
                float f = b2f(qf[kc][j]);
                qqf[kc][j] = f2b(f * f);
            }
        }

        float m_i[4], l_i[4];
        f32x4 o_acc[4] = {z, z, z, z};
        #pragma unroll
        for (int r = 0; r < 4; r++) { m_i[r] = NEG_BIG; l_i[r] = 0.f; }

        for (int jt = 0; jt <= it; jt++) {
            const int j0 = jt * 64;
            #pragma unroll
            for (int pass = 0; pass < 2; pass++) {
                int jr = sr2 + pass * 32;
                size_t rb = bh_base + (size_t)(j0 + jr) * (HH * DH) + sc2;
                *(int4*)&Gs[jr][sc2]  = *(const int4*)(G + rb);
                *(int4*)&GKs[jr][sc2] = *(const int4*)(GK + rb);
                int4 vvec = *(const int4*)(V + rb);
                const short* vv = (const short*)&vvec;
                #pragma unroll
                for (int jj = 0; jj < 8; jj++) Vt[sc2 + jj][jr ^ vswz] = vv[jj];
            }
            if (tid < 64) Cs[tid] = cj_row[j0 + tid];
            __syncthreads();

            f32x4 s1[4] = {z, z, z, z}, s2[4] = {z, z, z, z};
            #pragma unroll
            for (int ns = 0; ns < 4; ns++) {
                #pragma unroll
                for (int kc = 0; kc < 2; kc++) {
                    bf16x8 gf  = *(bf16x8*)&Gs [ns * 16 + l16][kc * 32 + quad * 8];
                    bf16x8 gkf = *(bf16x8*)&GKs[ns * 16 + l16][kc * 32 + quad * 8];
                    s1[ns] = __builtin_amdgcn_mfma_f32_16x16x32_bf16(qqf[kc], gf,  s1[ns], 0, 0, 0);
                    s2[ns] = __builtin_amdgcn_mfma_f32_16x16x32_bf16(qf[kc],  gkf, s2[ns], 0, 0, 0);
                }
            }

            float p[4][4];
            #pragma unroll
            for (int ns = 0; ns < 4; ns++) {
                float cjv = Cs[ns * 16 + l16];
                #pragma unroll
                for (int r = 0; r < 4; r++)
                    p[ns][r] = (2.f * s2[ns][r] - s1[ns][r] - cjv) * 0.125f;
            }
            if (jt == it) {
                #pragma unroll
                for (int ns = 0; ns < 4; ns++) {
                    int j = j0 + ns * 16 + l16;
                    #pragma unroll
                    for (int r = 0; r < 4; r++) {
                        int i = i0 + wave * 16 + quad * 4 + r;
                        if (j > i) p[ns][r] = NEG_BIG;
                    }
                }
            }

            #pragma unroll
            for (int r = 0; r < 4; r++) {
                float mx = fmaxf(fmaxf(p[0][r], p[1][r]), fmaxf(p[2][r], p[3][r]));
                #pragma unroll
                for (int d2 = 1; d2 < 16; d2 <<= 1) mx = fmaxf(mx, __shfl_xor(mx, d2));
                float mnew = fmaxf(m_i[r], mx);
                float corr = __expf(m_i[r] - mnew);
                float sp = 0.f;
                #pragma unroll
                for (int ns = 0; ns < 4; ns++) {
                    float e = __expf(p[ns][r] - mnew);
                    p[ns][r] = e; sp += e;
                }
                #pragma unroll
                for (int d2 = 1; d2 < 16; d2 <<= 1) sp += __shfl_xor(sp, d2);
                l_i[r] = l_i[r] * corr + sp;
                m_i[r] = mnew;
                #pragma unroll
                for (int nv = 0; nv < 4; nv++) o_acc[nv][r] *= corr;
            }

            #pragma unroll
            for (int ns = 0; ns < 4; ns++)
                #pragma unroll
                for (int r = 0; r < 4; r++)
                    Ps[wave][quad * 4 + r][ns * 16 + l16] = f2b(p[ns][r]);

            bf16x8 pf[2];
            pf[0] = *(bf16x8*)&Ps[wave][l16][quad * 8];
            pf[1] = *(bf16x8*)&Ps[wave][l16][32 + quad * 8];
            #pragma unroll
            for (int nv = 0; nv < 4; nv++) {
                const int vx = ((2 * nv + (l16 >> 3)) & 7) << 3;   // read-side XOR
                #pragma unroll
                for (int kc = 0; kc < 2; kc++) {
                    bf16x8 vf = *(bf16x8*)&Vt[nv * 16 + l16][(kc * 32 + quad * 8) ^ vx];
                    o_acc[nv] = __builtin_amdgcn_mfma_f32_16x16x32_bf16(pf[kc], vf, o_acc[nv], 0, 0, 0);
                }
            }
            __syncthreads();
        }

        #pragma unroll
        for (int nv = 0; nv < 4; nv++) {
            #pragma unroll
            for (int r = 0; r < 4; r++) {
                int i = i0 + wave * 16 + quad * 4 + r;
                int d = nv * 16 + l16;
                O[bh_base + (size_t)i * (HH * DH) + d] = f2b(o_acc[nv][r] / l_i[r]);
            }
        }
    }
}

// ------------------------------------------------------------------ launch ---
extern "C" void kernel_launch(void* const* d_in, const int* in_sizes, int n_in,
                              void* d_out, int out_size, void* d_ws, size_t ws_size,
                              hipStream_t stream)
{
    const float* x   = (const float*)d_in[0];
    const float* n1w = (const float*)d_in[1];
    const float* n2w = (const float*)d_in[2];
    const float* wq  = (const float*)d_in[3];
    const float* wk  = (const float*)d_in[4];
    const float* wv  = (const float*)d_in[5];
    const float* wo  = (const float*)d_in[6];
    const float* mw1 = (const float*)d_in[7];
    const float* mw2 = (const float*)d_in[8];
    const float* gw  = (const float*)d_in[9];
    const float* uw  = (const float*)d_in[10];
    const float* dw  = (const float*)d_in[11];
    float* out = (float*)d_out;   // fp32; holds x2 = x + attn@wo after wo-phase

    // Arena (48 MB known-safe; F widens to 32 MB iff ws_size >= 64 MB):
    //  slot0: h -> g -> h2 | slot1: qb -> WgT | slot2: kb/gk -> WuT
    //  slot3: vb -> WdT    | slot4(32-40): WfT(6.8M) -> ob; F overlays 32..
    //  slot5(40-48): woT(2M)@40 | m1(2M)@42 | cj(.25M)@44 | mw2T(.5M)@44.5 -> F
    const size_t MB = 1u << 20;
    if (ws_size < 48 * MB) return;
    const bool bigF = (ws_size >= 64 * MB);
    char* wsb = (char*)d_ws;
    short* h    = (short*)(wsb);
    short* g    = (short*)(wsb);
    short* h2   = (short*)(wsb);
    short* qb   = (short*)(wsb + 8 * MB);
    short* WgT  = (short*)(wsb + 8 * MB);
    short* kb   = (short*)(wsb + 16 * MB);
    short* WuT  = (short*)(wsb + 16 * MB);
    short* vb   = (short*)(wsb + 24 * MB);
    short* WdT  = (short*)(wsb + 24 * MB);
    short* WfT  = (short*)(wsb + 32 * MB);   // 3328x1024 bf16 = 6.8 MB
    short* ob   = (short*)(wsb + 32 * MB);
    short* F    = (short*)(wsb + 32 * MB);   // 16 MB (32 MB if bigF)
    short* woT  = (short*)(wsb + 40 * MB);
    short* m1   = (short*)(wsb + 42 * MB);
    float* cj   = (float*)(wsb + 44 * MB);
    short* mw2T = (short*)(wsb + 44 * MB + 512 * 1024);

    const int M = BB * TT;  // 4096 token rows

    // pre-attention weight transposes + rmsnorm1 (+ x->out copy), one dispatch
    pre_k<<<4608 + M, 256, 0, stream>>>(wq, wk, wv, mw1, wo, mw2,
                                        WfT, woT, mw2T, x, n1w, h, out);

    gemm128_qkvm_k<<<dim3(3328 / 128, M / 128), 256, 0, stream>>>(h, WfT, qb, kb, vb, m1);
    gemm128_k<EP_SOFTPLUS,false,false><<<dim3(DD / 128, M / 128), 256, 0, stream>>>(
        m1, mw2T, g, nullptr, DD, MHH, MHH, MHH);
    gkc_k<<<M, 256, 0, stream>>>(g, kb, cj);
    attn_k<<<dim3(8, BB * HH), 256, 0, stream>>>(qb, g, kb, vb, cj, ob);

    // out (= x) += ob @ wo  (split-K=2, fp32 atomic accumulate)
    gemm128_atomic_k<<<dim3(DD / 128, M / 128, 2), 256, 0, stream>>>(
        ob, woT, out, DD, 512, DD, DD);

    // FFN weight transposes + rmsnorm2, one dispatch (WgT/WuT/WdT overlay
    // qb/kb/vb -> must be after attn; rms2 needs out after wo-atomic)
    ffn_k<<<12288 + M, 256, 0, stream>>>(gw, uw, dw, WgT, WuT, WdT, out, n2w, h2);

    if (bigF) {   // one full-width SwiGLU (1024 blocks) + split-K=2 down
        gemm128_swiglu_k<<<dim3(DFF / 128, M / 128), 256, 0, stream>>>(h2, WgT, WuT, F, DFF, DD, DD);
        gemm128_atomic_k<<<dim3(DD / 128, M / 128, 2), 256, 0, stream>>>(
            F, WdT, out, DD, 2048, DFF, DFF);
    } else {      // two 2048-col halves, each with split-K=2 down
        const int NH = DFF / 2;
        for (int half = 0; half < 2; half++) {
            gemm128_swiglu_k<<<dim3(NH / 128, M / 128), 256, 0, stream>>>(
                h2, WgT + (size_t)half * NH * DD, WuT + (size_t)half * NH * DD, F, NH, DD, DD);
            gemm128_atomic_k<<<dim3(DD / 128, M / 128, 2), 256, 0, stream>>>(
                F, WdT + (size_t)half * NH, out, DD, 1024, NH, DFF);
        }
    }
}

// Round 11
// 451.157 us; speedup vs baseline: 1.2968x; 1.2120x over previous
//
#include <hip/hip_runtime.h>
#include <hip/hip_bf16.h>
#include <math.h>

// Problem dims
#define BB  4
#define TT  1024
#define DD  1024
#define HH  16
#define DH  64
#define DFF 4096
#define MHH 256

typedef __attribute__((ext_vector_type(8))) short bf16x8;   // 8 bf16 = 4 VGPRs
typedef __attribute__((ext_vector_type(4))) float f32x4;
typedef unsigned int u32;

#define NEG_BIG (-1e9f)

__device__ __forceinline__ float b2f(short s) {
    union { unsigned int u; float f; } x;
    x.u = ((unsigned int)(unsigned short)s) << 16;
    return x.f;
}
__device__ __forceinline__ short f2b(float f) {
    union { float f; unsigned int u; } x; x.f = f;
    unsigned int r = x.u + 0x7fffu + ((x.u >> 16) & 1u);   // RNE
    return (short)(r >> 16);
}
__device__ __forceinline__ float silu_f(float x) { return x / (1.f + __expf(-x)); }

// async global->LDS, 16B per lane. LDS dest must be wave_base + lane*16.
__device__ __forceinline__ void gld16(const short* g, short* l) {
    __builtin_amdgcn_global_load_lds(
        (const __attribute__((address_space(1))) u32*)g,
        (__attribute__((address_space(3))) u32*)l, 16, 0, 0);
}

// BK=64 staging: two BK=32 planes per buffer (proven layout per plane).
#define STAGE64(ga0, ga1, lds, kb)                                  \
    {                                                               \
        gld16((ga0) + (kb),      &(lds)[tid * 8]);                  \
        gld16((ga1) + (kb),      &(lds)[2048 + tid * 8]);           \
        gld16((ga0) + (kb) + 32, &(lds)[4096 + tid * 8]);           \
        gld16((ga1) + (kb) + 32, &(lds)[4096 + 2048 + tid * 8]);    \
    }

// ------------------- weight transpose tile: fp32 [K,N] -> bf16 [N,K] --------
__device__ __forceinline__ void convT_tile_body(
    const float* __restrict__ src, short* __restrict__ dst,
    int K, int N, int bx, int by, int tid, short (*Ts)[36])
{
    const int k0 = by * 32, n0 = bx * 32;
    const int r = tid >> 3, c4 = (tid & 7) * 4;
    float4 v = *(const float4*)(src + (size_t)(k0 + r) * N + n0 + c4);
    Ts[r][c4 + 0] = f2b(v.x); Ts[r][c4 + 1] = f2b(v.y);
    Ts[r][c4 + 2] = f2b(v.z); Ts[r][c4 + 3] = f2b(v.w);
    __syncthreads();
    short4 o;
    o.x = Ts[c4 + 0][r]; o.y = Ts[c4 + 1][r];
    o.z = Ts[c4 + 2][r]; o.w = Ts[c4 + 3][r];
    *(short4*)(dst + (size_t)(n0 + r) * K + k0 + c4) = o;
}

// ------------------------------- RMSNorm row body ---------------------------
// Optional XC: copy the fp32 input row to XC (folds the out=x memcpy into
// rmsnorm1's existing read of x). [verified r5]
__device__ __forceinline__ void rms_body(
    const float* __restrict__ X, const float* __restrict__ W,
    short* __restrict__ O, float* __restrict__ XC, int row, int tid, float* red)
{
    float4 xv = ((const float4*)(X + (size_t)row * DD))[tid];
    if (XC) ((float4*)(XC + (size_t)row * DD))[tid] = xv;
    float f0 = xv.x, f1 = xv.y, f2 = xv.z, f3 = xv.w;
    float ss = f0*f0 + f1*f1 + f2*f2 + f3*f3;
    #pragma unroll
    for (int m = 1; m < 64; m <<= 1) ss += __shfl_xor(ss, m);
    if ((tid & 63) == 0) red[tid >> 6] = ss;
    __syncthreads();
    float tot = red[0] + red[1] + red[2] + red[3];
    float scale = rsqrtf(tot * (1.f / DD) + 1e-6f);
    float4 wv = ((const float4*)W)[tid];
    short4 ov;
    ov.x = f2b(f0 * scale * wv.x);
    ov.y = f2b(f1 * scale * wv.y);
    ov.z = f2b(f2 * scale * wv.z);
    ov.w = f2b(f3 * scale * wv.w);
    ((short4*)(O + (size_t)row * DD))[tid] = ov;
}

// ---- fused pre-phase: weight transposes (4608 blocks) + rmsnorm1 (4096) ----
// Segments: wq(1024) wk(1024) wv(1024) mw1(256) wo(1024) mw2(256) | rms1(4096)
__global__ __launch_bounds__(256) void pre_k(
    const float* __restrict__ wq, const float* __restrict__ wk,
    const float* __restrict__ wv, const float* __restrict__ mw1,
    const float* __restrict__ wo, const float* __restrict__ mw2,
    short* __restrict__ WfT, short* __restrict__ woT, short* __restrict__ mw2T,
    const float* __restrict__ x, const float* __restrict__ n1w,
    short* __restrict__ h, float* __restrict__ out)
{
    __shared__ __align__(16) short Ts[32][36];
    __shared__ float red[4];
    const int b = blockIdx.x, tid = threadIdx.x;
    if (b >= 4608) { rms_body(x, n1w, h, out, b - 4608, tid, red); return; }
    const float* src; short* dst; int K, N, bx, by;
    if (b < 1024)      { src = wq;  dst = WfT;               K = DD;  N = DD;  int l = b;        bx = l & 31; by = l >> 5; }
    else if (b < 2048) { src = wk;  dst = WfT + 1024 * 1024; K = DD;  N = DD;  int l = b - 1024; bx = l & 31; by = l >> 5; }
    else if (b < 3072) { src = wv;  dst = WfT + 2048 * 1024; K = DD;  N = DD;  int l = b - 2048; bx = l & 31; by = l >> 5; }
    else if (b < 3328) { src = mw1; dst = WfT + 3072 * 1024; K = DD;  N = MHH; int l = b - 3072; bx = l & 7;  by = l >> 3; }
    else if (b < 4352) { src = wo;  dst = woT;               K = DD;  N = DD;  int l = b - 3328; bx = l & 31; by = l >> 5; }
    else               { src = mw2; dst = mw2T;              K = MHH; N = DD;  int l = b - 4352; bx = l & 31; by = l >> 5; }
    convT_tile_body(src, dst, K, N, bx, by, tid, Ts);
}

// ---- fused ffn-phase: gw/uw/dw transposes (12288 blocks) + rmsnorm2 (4096) -
__global__ __launch_bounds__(256) void ffn_k(
    const float* __restrict__ gw, const float* __restrict__ uw,
    const float* __restrict__ dw,
    short* __restrict__ WgT, short* __restrict__ WuT, short* __restrict__ WdT,
    const float* __restrict__ out, const float* __restrict__ n2w,
    short* __restrict__ h2)
{
    __shared__ __align__(16) short Ts[32][36];
    __shared__ float red[4];
    const int b = blockIdx.x, tid = threadIdx.x;
    if (b >= 12288) { rms_body(out, n2w, h2, nullptr, b - 12288, tid, red); return; }
    const float* src; short* dst; int K, N, bx, by;
    if (b < 4096)      { src = gw; dst = WgT; K = DD;  N = DFF; int l = b;        bx = l & 127; by = l >> 7; }
    else if (b < 8192) { src = uw; dst = WuT; K = DD;  N = DFF; int l = b - 4096; bx = l & 127; by = l >> 7; }
    else               { src = dw; dst = WdT; K = DFF; N = DD;  int l = b - 8192; bx = l & 31;  by = l >> 5; }
    convT_tile_body(src, dst, K, N, bx, by, tid, Ts);
}

// ------------- split-K 128x128 GEMM BK=64, fp32 atomic accumulate into out --
// __launch_bounds__(256, 4): single-acc body fits <=128 regs -> 4 waves/SIMD.
__global__ __launch_bounds__(256, 4) void gemm128_atomic_k(
    const short* __restrict__ A, const short* __restrict__ Bt,
    float* out, int N, int Kc, int lda, int ldb)
{
    __shared__ __align__(16) short As[2 * 4096];
    __shared__ __align__(16) short Bs[2 * 4096];
    const int tid  = threadIdx.x;
    const int wave = tid >> 6, lane = tid & 63;
    const int l16  = lane & 15, quad = lane >> 4;
    const int m0 = blockIdx.y * 128, n0 = blockIdx.x * 128;
    const int wm = (wave & 1) * 64, wn = (wave >> 1) * 64;
    const int koff = blockIdx.z * Kc;

    f32x4 acc[4][4];
    #pragma unroll
    for (int i = 0; i < 4; i++)
        #pragma unroll
        for (int j = 0; j < 4; j++) acc[i][j] = (f32x4){0.f, 0.f, 0.f, 0.f};

    const int srow = tid >> 2, scol = (tid & 3) * 8;
    const short* ga0 = A  + (size_t)(m0 + srow)      * lda + koff + scol;
    const short* ga1 = A  + (size_t)(m0 + 64 + srow) * lda + koff + scol;
    const short* gb0 = Bt + (size_t)(n0 + srow)      * ldb + koff + scol;
    const short* gb1 = Bt + (size_t)(n0 + 64 + srow) * ldb + koff + scol;

    for (int kb = 0; kb < Kc; kb += 64) {
        STAGE64(ga0, ga1, As, kb);
        STAGE64(gb0, gb1, Bs, kb);
        __syncthreads();
        #pragma unroll
        for (int kc = 0; kc < 2; kc++) {
            bf16x8 af[4], bf[4];
            #pragma unroll
            for (int mi = 0; mi < 4; mi++)
                af[mi] = *(bf16x8*)&As[kc * 4096 + (wm + mi * 16 + l16) * 32 + quad * 8];
            #pragma unroll
            for (int ni = 0; ni < 4; ni++)
                bf[ni] = *(bf16x8*)&Bs[kc * 4096 + (wn + ni * 16 + l16) * 32 + quad * 8];
            #pragma unroll
            for (int mi = 0; mi < 4; mi++)
                #pragma unroll
                for (int ni = 0; ni < 4; ni++)
                    acc[mi][ni] = __builtin_amdgcn_mfma_f32_16x16x32_bf16(af[mi], bf[ni], acc[mi][ni], 0, 0, 0);
        }
        __syncthreads();
    }
    #pragma unroll
    for (int mi = 0; mi < 4; mi++)
        #pragma unroll
        for (int ni = 0; ni < 4; ni++)
            #pragma unroll
            for (int r = 0; r < 4; r++) {
                int row = m0 + wm + mi * 16 + quad * 4 + r;
                int col = n0 + wn + ni * 16 + l16;
                atomicAdd(out + (size_t)row * N + col, acc[mi][ni][r]);
            }
}

// --------------- fused QKV+mnet1 GEMM: N=3328 packed weights, BK=64 ---------
// Wf rows: [0,1024)=wq^T, [1024,2048)=wk^T, [2048,3072)=wv^T, [3072,3328)=mw1^T
__global__ __launch_bounds__(256, 4) void gemm128_qkvm_k(
    const short* __restrict__ A, const short* __restrict__ Wf,
    short* __restrict__ Qb, short* __restrict__ Kb, short* __restrict__ Vb,
    short* __restrict__ M1)
{
    __shared__ __align__(16) short As[2 * 4096];
    __shared__ __align__(16) short Bs[2 * 4096];
    const int tid  = threadIdx.x;
    const int wave = tid >> 6, lane = tid & 63;
    const int l16  = lane & 15, quad = lane >> 4;
    const int m0 = blockIdx.y * 128, n0 = blockIdx.x * 128;
    const int wm = (wave & 1) * 64, wn = (wave >> 1) * 64;
    const int K = DD;

    f32x4 acc[4][4];
    #pragma unroll
    for (int i = 0; i < 4; i++)
        #pragma unroll
        for (int j = 0; j < 4; j++) acc[i][j] = (f32x4){0.f, 0.f, 0.f, 0.f};

    const int srow = tid >> 2, scol = (tid & 3) * 8;
    const short* ga0 = A  + (size_t)(m0 + srow)      * K + scol;
    const short* ga1 = A  + (size_t)(m0 + 64 + srow) * K + scol;
    const short* gb0 = Wf + (size_t)(n0 + srow)      * K + scol;
    const short* gb1 = Wf + (size_t)(n0 + 64 + srow) * K + scol;

    for (int kb = 0; kb < K; kb += 64) {
        STAGE64(ga0, ga1, As, kb);
        STAGE64(gb0, gb1, Bs, kb);
        __syncthreads();
        #pragma unroll
        for (int kc = 0; kc < 2; kc++) {
            bf16x8 af[4], bf[4];
            #pragma unroll
            for (int mi = 0; mi < 4; mi++)
                af[mi] = *(bf16x8*)&As[kc * 4096 + (wm + mi * 16 + l16) * 32 + quad * 8];
            #pragma unroll
            for (int ni = 0; ni < 4; ni++)
                bf[ni] = *(bf16x8*)&Bs[kc * 4096 + (wn + ni * 16 + l16) * 32 + quad * 8];
            #pragma unroll
            for (int mi = 0; mi < 4; mi++)
                #pragma unroll
                for (int ni = 0; ni < 4; ni++)
                    acc[mi][ni] = __builtin_amdgcn_mfma_f32_16x16x32_bf16(af[mi], bf[ni], acc[mi][ni], 0, 0, 0);
        }
        __syncthreads();
    }
    short* dst; int base, ldc; bool dosilu = false;
    if      (n0 < 1024) { dst = Qb; base = 0;    ldc = 1024; }
    else if (n0 < 2048) { dst = Kb; base = 1024; ldc = 1024; }
    else if (n0 < 3072) { dst = Vb; base = 2048; ldc = 1024; }
    else                { dst = M1; base = 3072; ldc = 256; dosilu = true; }
    #pragma unroll
    for (int mi = 0; mi < 4; mi++)
        #pragma unroll
        for (int ni = 0; ni < 4; ni++)
            #pragma unroll
            for (int r = 0; r < 4; r++) {
                int row = m0 + wm + mi * 16 + quad * 4 + r;
                int col = n0 + wn + ni * 16 + l16 - base;
                float v = acc[mi][ni][r];
                if (dosilu) v = silu_f(v);
                dst[(size_t)row * ldc + col] = f2b(v);
            }
}

// ------- mnet2 GEMM: 64x128 tile, BK=64, K=256, fused softplus epilogue -----
// The 128x128 shape gave grid 8x32 = 256 blocks = exactly 1 block/CU with only
// 4 K-steps: zero cross-block latency overlap (measured r10: 96us, MfmaUtil
// 0.8%). 64-row tiles double the grid (8x64 = 512 = 2 blocks/CU), restoring
// the cross-block overlap every other GEMM here relies on. B-side staging and
// fragment math identical to the proven 128-row body; A-side is the same
// layout at 64 rows (2 planes of 64x32 = one gld16 each). Waves 2x2:
// wm=(w&1)*32, wn=(w>>1)*64, acc[2][4].
__global__ __launch_bounds__(256, 4) void gemm_mnet2h_k(
    const short* __restrict__ A, const short* __restrict__ Bt,
    short* __restrict__ G)
{
    __shared__ __align__(16) short As[2 * 2048];   // 2 planes of 64x32
    __shared__ __align__(16) short Bs[2 * 4096];   // 2 planes of 128x32
    const int tid  = threadIdx.x;
    const int wave = tid >> 6, lane = tid & 63;
    const int l16  = lane & 15, quad = lane >> 4;
    const int m0 = blockIdx.y * 64, n0 = blockIdx.x * 128;
    const int wm = (wave & 1) * 32, wn = (wave >> 1) * 64;
    const int K = MHH;

    f32x4 acc[2][4];
    #pragma unroll
    for (int i = 0; i < 2; i++)
        #pragma unroll
        for (int j = 0; j < 4; j++) acc[i][j] = (f32x4){0.f, 0.f, 0.f, 0.f};

    const int srow = tid >> 2, scol = (tid & 3) * 8;
    const short* ga  = A  + (size_t)(m0 + srow)      * K + scol;   // 64 rows
    const short* gb0 = Bt + (size_t)(n0 + srow)      * K + scol;
    const short* gb1 = Bt + (size_t)(n0 + 64 + srow) * K + scol;

    for (int kb = 0; kb < K; kb += 64) {
        gld16(ga + kb,      &As[tid * 8]);          // plane 0: k in [kb,kb+32)
        gld16(ga + kb + 32, &As[2048 + tid * 8]);   // plane 1: k in [kb+32,kb+64)
        STAGE64(gb0, gb1, Bs, kb);
        __syncthreads();
        #pragma unroll
        for (int kc = 0; kc < 2; kc++) {
            bf16x8 af[2], bf[4];
            #pragma unroll
            for (int mi = 0; mi < 2; mi++)
                af[mi] = *(bf16x8*)&As[kc * 2048 + (wm + mi * 16 + l16) * 32 + quad * 8];
            #pragma unroll
            for (int ni = 0; ni < 4; ni++)
                bf[ni] = *(bf16x8*)&Bs[kc * 4096 + (wn + ni * 16 + l16) * 32 + quad * 8];
            #pragma unroll
            for (int mi = 0; mi < 2; mi++)
                #pragma unroll
                for (int ni = 0; ni < 4; ni++)
                    acc[mi][ni] = __builtin_amdgcn_mfma_f32_16x16x32_bf16(af[mi], bf[ni], acc[mi][ni], 0, 0, 0);
        }
        __syncthreads();
    }
    #pragma unroll
    for (int mi = 0; mi < 2; mi++)
        #pragma unroll
        for (int ni = 0; ni < 4; ni++)
            #pragma unroll
            for (int r = 0; r < 4; r++) {
                int row = m0 + wm + mi * 16 + quad * 4 + r;
                int col = n0 + wn + ni * 16 + l16;
                float v = acc[mi][ni][r];
                v = fmaxf(v, 0.f) + log1pf(__expf(-fabsf(v)));   // softplus
                G[(size_t)row * DD + col] = f2b(v);
            }
}

// ------------------------- 128x128 fused SwiGLU (gate & up) GEMM, BK=64 -----
// __launch_bounds__(256, 2): dual acc (128 acc regs) overflows 256 total at
// default build -> 1 wave/SIMD. Forcing 2 waves/EU doubles occupancy.
// [verified r4/r5: 133 -> 76 us, MfmaUtil 37% = 2-phase structure ceiling]
__global__ __launch_bounds__(256, 2) void gemm128_swiglu_k(
    const short* __restrict__ A, const short* __restrict__ Gt,
    const short* __restrict__ Ut, short* __restrict__ F,
    int N, int K, int ldb)
{
    __shared__ __align__(16) short As[2 * 4096];
    __shared__ __align__(16) short Gs[2 * 4096];
    __shared__ __align__(16) short Us[2 * 4096];
    const int tid  = threadIdx.x;
    const int wave = tid >> 6, lane = tid & 63;
    const int l16  = lane & 15, quad = lane >> 4;

    int bx = blockIdx.x, by = blockIdx.y;
    {
        const int gx = gridDim.x;
        if ((gx & 7) == 0) {
            const int orig = by * gx + bx;          // x-fastest dispatch order
            const int xcd = orig & 7, j = orig >> 3;
            const int xpx = gx >> 3;                // n-tiles per XCD
            bx = xcd * xpx + (j % xpx);
            by = j / xpx;
        }
    }
    const int m0 = by * 128, n0 = bx * 128;
    const int wm = (wave & 1) * 64, wn = (wave >> 1) * 64;

    f32x4 ag[4][4], au[4][4];
    #pragma unroll
    for (int i = 0; i < 4; i++)
        #pragma unroll
        for (int j = 0; j < 4; j++) {
            ag[i][j] = (f32x4){0.f, 0.f, 0.f, 0.f};
            au[i][j] = (f32x4){0.f, 0.f, 0.f, 0.f};
        }

    const int srow = tid >> 2, scol = (tid & 3) * 8;
    const short* ga0 = A  + (size_t)(m0 + srow)      * K   + scol;
    const short* ga1 = A  + (size_t)(m0 + 64 + srow) * K   + scol;
    const short* gg0 = Gt + (size_t)(n0 + srow)      * ldb + scol;
    const short* gg1 = Gt + (size_t)(n0 + 64 + srow) * ldb + scol;
    const short* gu0 = Ut + (size_t)(n0 + srow)      * ldb + scol;
    const short* gu1 = Ut + (size_t)(n0 + 64 + srow) * ldb + scol;

    for (int kb = 0; kb < K; kb += 64) {
        STAGE64(ga0, ga1, As, kb);
        STAGE64(gg0, gg1, Gs, kb);
        STAGE64(gu0, gu1, Us, kb);
        __syncthreads();
        #pragma unroll
        for (int kc = 0; kc < 2; kc++) {
            bf16x8 af[4], gf[4], uf[4];
            #pragma unroll
            for (int mi = 0; mi < 4; mi++)
                af[mi] = *(bf16x8*)&As[kc * 4096 + (wm + mi * 16 + l16) * 32 + quad * 8];
            #pragma unroll
            for (int ni = 0; ni < 4; ni++) {
                gf[ni] = *(bf16x8*)&Gs[kc * 4096 + (wn + ni * 16 + l16) * 32 + quad * 8];
                uf[ni] = *(bf16x8*)&Us[kc * 4096 + (wn + ni * 16 + l16) * 32 + quad * 8];
            }
            #pragma unroll
            for (int mi = 0; mi < 4; mi++)
                #pragma unroll
                for (int ni = 0; ni < 4; ni++) {
                    ag[mi][ni] = __builtin_amdgcn_mfma_f32_16x16x32_bf16(af[mi], gf[ni], ag[mi][ni], 0, 0, 0);
                    au[mi][ni] = __builtin_amdgcn_mfma_f32_16x16x32_bf16(af[mi], uf[ni], au[mi][ni], 0, 0, 0);
                }
        }
        __syncthreads();
    }
    #pragma unroll
    for (int mi = 0; mi < 4; mi++)
        #pragma unroll
        for (int ni = 0; ni < 4; ni++)
            #pragma unroll
            for (int r = 0; r < 4; r++) {
                int row = m0 + wm + mi * 16 + quad * 4 + r;
                int col = n0 + wn + ni * 16 + l16;
                F[(size_t)row * N + col] = f2b(silu_f(ag[mi][ni][r]) * au[mi][ni][r]);
            }
}

// ------------------------------------- gk = g*k in-place, c = sum gk*k ------
__global__ __launch_bounds__(256) void gkc_k(
    const short* __restrict__ G, short* KG,
    float* __restrict__ Cj)
{
    const int bt  = blockIdx.x;
    const int tid = threadIdx.x;
    const int h = tid >> 4, d0 = (tid & 15) * 4;
    const size_t base = (size_t)bt * (HH * DH) + h * DH + d0;
    short4 gv = *(const short4*)(G + base);
    short4 kv = *(const short4*)(KG + base);
    float g0 = b2f(gv.x), g1 = b2f(gv.y), g2 = b2f(gv.z), g3 = b2f(gv.w);
    float k0 = b2f(kv.x), k1 = b2f(kv.y), k2 = b2f(kv.z), k3 = b2f(kv.w);
    float p0 = g0*k0, p1 = g1*k1, p2 = g2*k2, p3 = g3*k3;
    short4 ov; ov.x = f2b(p0); ov.y = f2b(p1); ov.z = f2b(p2); ov.w = f2b(p3);
    *(short4*)(KG + base) = ov;
    float cc = p0*k0 + p1*k1 + p2*k2 + p3*k3;
    #pragma unroll
    for (int m = 1; m < 16; m <<= 1) cc += __shfl_xor(cc, m);
    if ((tid & 15) == 0) {
        int b = bt >> 10, t = bt & (TT - 1);
        Cj[((size_t)b * HH + h) * TT + t] = cc;
    }
}

// -------------------------------------------------- flash geodesic attention -
// (r7-exact body: the r9 Vt swizzle is reverted to restore the validated
// 461us build and shrink the co-compile perturbation surface.)
__global__ __launch_bounds__(256) void attn_k(
    const short* __restrict__ Q, const short* __restrict__ G,
    const short* __restrict__ GK, const short* __restrict__ V,
    const float* __restrict__ Cj, short* __restrict__ O)
{
    __shared__ __align__(16) short Gs[64][72];
    __shared__ __align__(16) short GKs[64][72];
    __shared__ __align__(16) short Vt[64][72];
    __shared__ __align__(16) float Cs[64];
    __shared__ __align__(16) short Ps[4][16][72];

    const int pair = blockIdx.x;          // 0..7
    const int bh = blockIdx.y;
    const int b = bh >> 4, h = bh & 15;
    const int tid  = threadIdx.x;
    const int wave = tid >> 6, lane = tid & 63;
    const int l16  = lane & 15, quad = lane >> 4;

    const size_t bh_base = ((size_t)b * TT) * (HH * DH) + (size_t)h * DH;
    const float* cj_row = Cj + ((size_t)b * HH + h) * TT;

    const int sr2 = tid >> 3, sc2 = (tid & 7) * 8;
    const f32x4 z = {0.f, 0.f, 0.f, 0.f};

    for (int halfsel = 0; halfsel < 2; halfsel++) {
        const int it = halfsel ? 15 - pair : pair;
        const int i0 = it * 64;

        const int qrow = i0 + wave * 16 + l16;
        bf16x8 qf[2], qqf[2];
        #pragma unroll
        for (int kc = 0; kc < 2; kc++) {
            qf[kc] = *(const bf16x8*)(Q + bh_base + (size_t)qrow * (HH * DH) + kc * 32 + quad * 8);
            #pragma unroll
            for (int j = 0; j < 8; j++) {
                float f = b2f(qf[kc][j]);
                qqf[kc][j] = f2b(f * f);
            }
        }

        float m_i[4], l_i[4];
        f32x4 o_acc[4] = {z, z, z, z};
        #pragma unroll
        for (int r = 0; r < 4; r++) { m_i[r] = NEG_BIG; l_i[r] = 0.f; }

        for (int jt = 0; jt <= it; jt++) {
            const int j0 = jt * 64;
            #pragma unroll
            for (int pass = 0; pass < 2; pass++) {
                int jr = sr2 + pass * 32;
                size_t rb = bh_base + (size_t)(j0 + jr) * (HH * DH) + sc2;
                *(int4*)&Gs[jr][sc2]  = *(const int4*)(G + rb);
                *(int4*)&GKs[jr][sc2] = *(const int4*)(GK + rb);
                int4 vvec = *(const int4*)(V + rb);
                const short* vv = (const short*)&vvec;
                #pragma unroll
                for (int jj = 0; jj < 8; jj++) Vt[sc2 + jj][jr] = vv[jj];
            }
            if (tid < 64) Cs[tid] = cj_row[j0 + tid];
            __syncthreads();

            f32x4 s1[4] = {z, z, z, z}, s2[4] = {z, z, z, z};
            #pragma unroll
            for (int ns = 0; ns < 4; ns++) {
                #pragma unroll
                for (int kc = 0; kc < 2; kc++) {
                    bf16x8 gf  = *(bf16x8*)&Gs [ns * 16 + l16][kc * 32 + quad * 8];
                    bf16x8 gkf = *(bf16x8*)&GKs[ns * 16 + l16][kc * 32 + quad * 8];
                    s1[ns] = __builtin_amdgcn_mfma_f32_16x16x32_bf16(qqf[kc], gf,  s1[ns], 0, 0, 0);
                    s2[ns] = __builtin_amdgcn_mfma_f32_16x16x32_bf16(qf[kc],  gkf, s2[ns], 0, 0, 0);
                }
            }

            float p[4][4];
            #pragma unroll
            for (int ns = 0; ns < 4; ns++) {
                float cjv = Cs[ns * 16 + l16];
                #pragma unroll
                for (int r = 0; r < 4; r++)
                    p[ns][r] = (2.f * s2[ns][r] - s1[ns][r] - cjv) * 0.125f;
            }
            if (jt == it) {
                #pragma unroll
                for (int ns = 0; ns < 4; ns++) {
                    int j = j0 + ns * 16 + l16;
                    #pragma unroll
                    for (int r = 0; r < 4; r++) {
                        int i = i0 + wave * 16 + quad * 4 + r;
                        if (j > i) p[ns][r] = NEG_BIG;
                    }
                }
            }

            #pragma unroll
            for (int r = 0; r < 4; r++) {
                float mx = fmaxf(fmaxf(p[0][r], p[1][r]), fmaxf(p[2][r], p[3][r]));
                #pragma unroll
                for (int d2 = 1; d2 < 16; d2 <<= 1) mx = fmaxf(mx, __shfl_xor(mx, d2));
                float mnew = fmaxf(m_i[r], mx);
                float corr = __expf(m_i[r] - mnew);
                float sp = 0.f;
                #pragma unroll
                for (int ns = 0; ns < 4; ns++) {
                    float e = __expf(p[ns][r] - mnew);
                    p[ns][r] = e; sp += e;
                }
                #pragma unroll
                for (int d2 = 1; d2 < 16; d2 <<= 1) sp += __shfl_xor(sp, d2);
                l_i[r] = l_i[r] * corr + sp;
                m_i[r] = mnew;
                #pragma unroll
                for (int nv = 0; nv < 4; nv++) o_acc[nv][r] *= corr;
            }

            #pragma unroll
            for (int ns = 0; ns < 4; ns++)
                #pragma unroll
                for (int r = 0; r < 4; r++)
                    Ps[wave][quad * 4 + r][ns * 16 + l16] = f2b(p[ns][r]);

            bf16x8 pf[2];
            pf[0] = *(bf16x8*)&Ps[wave][l16][quad * 8];
            pf[1] = *(bf16x8*)&Ps[wave][l16][32 + quad * 8];
            #pragma unroll
            for (int nv = 0; nv < 4; nv++) {
                #pragma unroll
                for (int kc = 0; kc < 2; kc++) {
                    bf16x8 vf = *(bf16x8*)&Vt[nv * 16 + l16][kc * 32 + quad * 8];
                    o_acc[nv] = __builtin_amdgcn_mfma_f32_16x16x32_bf16(pf[kc], vf, o_acc[nv], 0, 0, 0);
                }
            }
            __syncthreads();
        }

        #pragma unroll
        for (int nv = 0; nv < 4; nv++) {
            #pragma unroll
            for (int r = 0; r < 4; r++) {
                int i = i0 + wave * 16 + quad * 4 + r;
                int d = nv * 16 + l16;
                O[bh_base + (size_t)i * (HH * DH) + d] = f2b(o_acc[nv][r] / l_i[r]);
            }
        }
    }
}

// ------------------------------------------------------------------ launch ---
extern "C" void kernel_launch(void* const* d_in, const int* in_sizes, int n_in,
                              void* d_out, int out_size, void* d_ws, size_t ws_size,
                              hipStream_t stream)
{
    const float* x   = (const float*)d_in[0];
    const float* n1w = (const float*)d_in[1];
    const float* n2w = (const float*)d_in[2];
    const float* wq  = (const float*)d_in[3];
    const float* wk  = (const float*)d_in[4];
    const float* wv  = (const float*)d_in[5];
    const float* wo  = (const float*)d_in[6];
    const float* mw1 = (const float*)d_in[7];
    const float* mw2 = (const float*)d_in[8];
    const float* gw  = (const float*)d_in[9];
    const float* uw  = (const float*)d_in[10];
    const float* dw  = (const float*)d_in[11];
    float* out = (float*)d_out;   // fp32; holds x2 = x + attn@wo after wo-phase

    // Arena (48 MB known-safe; F widens to 32 MB iff ws_size >= 64 MB):
    //  slot0: h -> g -> h2 | slot1: qb -> WgT | slot2: kb/gk -> WuT
    //  slot3: vb -> WdT    | slot4(32-40): WfT(6.8M) -> ob; F overlays 32..
    //  slot5(40-48): woT(2M)@40 | m1(2M)@42 | cj(.25M)@44 | mw2T(.5M)@44.5 -> F
    const size_t MB = 1u << 20;
    if (ws_size < 48 * MB) return;
    const bool bigF = (ws_size >= 64 * MB);
    char* wsb = (char*)d_ws;
    short* h    = (short*)(wsb);
    short* g    = (short*)(wsb);
    short* h2   = (short*)(wsb);
    short* qb   = (short*)(wsb + 8 * MB);
    short* WgT  = (short*)(wsb + 8 * MB);
    short* kb   = (short*)(wsb + 16 * MB);
    short* WuT  = (short*)(wsb + 16 * MB);
    short* vb   = (short*)(wsb + 24 * MB);
    short* WdT  = (short*)(wsb + 24 * MB);
    short* WfT  = (short*)(wsb + 32 * MB);   // 3328x1024 bf16 = 6.8 MB
    short* ob   = (short*)(wsb + 32 * MB);
    short* F    = (short*)(wsb + 32 * MB);   // 16 MB (32 MB if bigF)
    short* woT  = (short*)(wsb + 40 * MB);
    short* m1   = (short*)(wsb + 42 * MB);
    float* cj   = (float*)(wsb + 44 * MB);
    short* mw2T = (short*)(wsb + 44 * MB + 512 * 1024);

    const int M = BB * TT;  // 4096 token rows

    // pre-attention weight transposes + rmsnorm1 (+ x->out copy), one dispatch
    pre_k<<<4608 + M, 256, 0, stream>>>(wq, wk, wv, mw1, wo, mw2,
                                        WfT, woT, mw2T, x, n1w, h, out);

    gemm128_qkvm_k<<<dim3(3328 / 128, M / 128), 256, 0, stream>>>(h, WfT, qb, kb, vb, m1);

    // mnet2: 64-row tiles -> 512 blocks = 2 blocks/CU (latency-robust shape)
    gemm_mnet2h_k<<<dim3(DD / 128, M / 64), 256, 0, stream>>>(m1, mw2T, g);

    gkc_k<<<M, 256, 0, stream>>>(g, kb, cj);
    attn_k<<<dim3(8, BB * HH), 256, 0, stream>>>(qb, g, kb, vb, cj, ob);

    // out (= x) += ob @ wo  (split-K=2, fp32 atomic accumulate)
    gemm128_atomic_k<<<dim3(DD / 128, M / 128, 2), 256, 0, stream>>>(
        ob, woT, out, DD, 512, DD, DD);

    // FFN weight transposes + rmsnorm2, one dispatch (WgT/WuT/WdT overlay
    // qb/kb/vb -> must be after attn; rms2 needs out after wo-atomic)
    ffn_k<<<12288 + M, 256, 0, stream>>>(gw, uw, dw, WgT, WuT, WdT, out, n2w, h2);

    if (bigF) {   // one full-width SwiGLU (1024 blocks) + split-K=2 down
        gemm128_swiglu_k<<<dim3(DFF / 128, M / 128), 256, 0, stream>>>(h2, WgT, WuT, F, DFF, DD, DD);
        gemm128_atomic_k<<<dim3(DD / 128, M / 128, 2), 256, 0, stream>>>(
            F, WdT, out, DD, 2048, DFF, DFF);
    } else {      // two 2048-col halves, each with split-K=2 down
        const int NH = DFF / 2;
        for (int half = 0; half < 2; half++) {
            gemm128_swiglu_k<<<dim3(NH / 128, M / 128), 256, 0, stream>>>(
                h2, WgT + (size_t)half * NH * DD, WuT + (size_t)half * NH * DD, F, NH, DD, DD);
            gemm128_atomic_k<<<dim3(DD / 128, M / 128, 2), 256, 0, stream>>>(
                F, WdT + (size_t)half * NH, out, DD, 1024, NH, DFF);
        }
    }
}